// Round 2
// baseline (3398.828 us; speedup 1.0000x reference)
//
#include <hip/hip_runtime.h>
#include <hip/hip_bf16.h>
#include <math.h>

#define B_TOTAL 40960
#define NGRP 20
#define GSZ 2048
#define HPAD 68   // LDS row stride (floats) for transposed activation tiles

// ---------------- group scatter ----------------
__global__ void k_scatter(const int* __restrict__ bid, int* __restrict__ grp,
                          int* __restrict__ cnt)
{
    int i = blockIdx.x * 256 + threadIdx.x;
    if (i < B_TOTAL) {
        int g = bid[i];
        int p = atomicAdd(&cnt[g], 1);
        grp[g * GSZ + p] = i;
    }
}

// ---------------- kNN stage 1: gather coords transposed + norms ----------------
__global__ __launch_bounds__(256) void k_gather(const float* __restrict__ x,
    const int* __restrict__ grp, float* __restrict__ xgT, float* __restrict__ norms)
{
    __shared__ float tile[128][65];
    __shared__ int ids[128];
    const int tid = threadIdx.x;
    const int g = blockIdx.y;
    const int q0 = blockIdx.x * 128;
    if (tid < 128) ids[tid] = grp[g * GSZ + q0 + tid];
    __syncthreads();
    for (int s = tid; s < 128 * 64; s += 256) {
        int q = s >> 6, d = s & 63;
        tile[q][d] = (d < 63) ? x[(size_t)ids[q] * 90 + d] : 0.f;
    }
    __syncthreads();
    if (tid < 128) {
        float a = 0.f;
        #pragma unroll
        for (int d = 0; d < 63; d++) a = fmaf(tile[tid][d], tile[tid][d], a);
        norms[g * GSZ + q0 + tid] = a;
    }
    for (int s = tid; s < 63 * 128; s += 256) {
        int d = s >> 7, q = s & 127;
        xgT[((size_t)g * 63 + d) * GSZ + q0 + q] = tile[q][d];
    }
}

// ---------------- top-3 insert ----------------
__device__ __forceinline__ void ins3(float d, int p,
    float& v0, float& v1, float& v2, int& p0, int& p1, int& p2)
{
    if (d < v0)      { v2 = v1; p2 = p1; v1 = v0; p1 = p0; v0 = d; p0 = p; }
    else if (d < v1) { v2 = v1; p2 = p1; v1 = d;  p1 = p; }
    else if (d < v2) { v2 = d;  p2 = p; }
}

// ---------------- kNN stage 2: tiled distance GEMM + partial top3 ----------------
// grid: (cand tile 0..7, query tile 0..31, group 0..19)
__global__ __launch_bounds__(256) void k_knn_gemm(const float* __restrict__ xgT,
    const float* __restrict__ norms, float* __restrict__ pval, int* __restrict__ pidx)
{
    __shared__ float aT[63][72];     // queries^T
    __shared__ float bb[16][256];    // candidate k-chunk
    __shared__ float qnS[64];
    __shared__ float cnS[256];
    const int tid = threadIdx.x;
    const int tx = tid & 31, ty = tid >> 5;
    const int ct0 = tx * 8, r0 = ty * 8;
    const int g = blockIdx.z;
    const int q0 = blockIdx.y * 64;
    const int c0 = blockIdx.x * 256;
    const float* base = xgT + (size_t)g * 63 * GSZ;

    for (int s = tid; s < 63 * 64; s += 256) {
        int d = s >> 6, q = s & 63;
        aT[d][q] = base[(size_t)d * GSZ + q0 + q];
    }
    if (tid < 64) qnS[tid] = norms[g * GSZ + q0 + tid];
    cnS[tid] = norms[g * GSZ + c0 + tid];

    float acc[8][8];
    #pragma unroll
    for (int i = 0; i < 8; i++)
        #pragma unroll
        for (int j = 0; j < 8; j++) acc[i][j] = 0.f;

    for (int k0 = 0; k0 < 63; k0 += 16) {
        const int kc = (63 - k0 < 16) ? (63 - k0) : 16;
        __syncthreads();
        for (int s = tid; s < (kc << 8); s += 256) {
            int kk = s >> 8, c = s & 255;
            bb[kk][c] = base[(size_t)(k0 + kk) * GSZ + c0 + c];
        }
        __syncthreads();
        for (int kk = 0; kk < kc; kk++) {
            float4 a0 = *(const float4*)&aT[k0 + kk][r0];
            float4 a1 = *(const float4*)&aT[k0 + kk][r0 + 4];
            float4 b0v = *(const float4*)&bb[kk][ct0];
            float4 b1v = *(const float4*)&bb[kk][ct0 + 4];
            float av[8] = {a0.x,a0.y,a0.z,a0.w,a1.x,a1.y,a1.z,a1.w};
            float bv[8] = {b0v.x,b0v.y,b0v.z,b0v.w,b1v.x,b1v.y,b1v.z,b1v.w};
            #pragma unroll
            for (int i = 0; i < 8; i++)
                #pragma unroll
                for (int j = 0; j < 8; j++)
                    acc[i][j] = fmaf(av[i], bv[j], acc[i][j]);
        }
    }

    #pragma unroll
    for (int i = 0; i < 8; i++) {
        const int qpos = q0 + r0 + i;
        const float qn = qnS[r0 + i];
        float v0 = 1e30f, v1 = 1e30f, v2 = 1e30f;
        int   p0 = 0, p1 = 0, p2 = 0;
        #pragma unroll
        for (int j = 0; j < 8; j++) {
            int cpos = c0 + ct0 + j;
            float d2 = qn + cnS[ct0 + j] - 2.f * acc[i][j];
            if (cpos != qpos) ins3(d2, cpos, v0, v1, v2, p0, p1, p2);
        }
        #pragma unroll
        for (int m = 1; m <= 16; m <<= 1) {
            float o0 = __shfl_xor(v0, m), o1 = __shfl_xor(v1, m), o2 = __shfl_xor(v2, m);
            int   q0_ = __shfl_xor(p0, m), q1_ = __shfl_xor(p1, m), q2_ = __shfl_xor(p2, m);
            ins3(o0, q0_, v0, v1, v2, p0, p1, p2);
            ins3(o1, q1_, v0, v1, v2, p0, p1, p2);
            ins3(o2, q2_, v0, v1, v2, p0, p1, p2);
        }
        if (tx == 0) {
            size_t off = (((size_t)g * GSZ + qpos) * 8 + blockIdx.x) * 3;
            pval[off + 0] = v0; pidx[off + 0] = p0;
            pval[off + 1] = v1; pidx[off + 1] = p1;
            pval[off + 2] = v2; pidx[off + 2] = p2;
        }
    }
}

// ---------------- kNN stage 3: merge 8 partials, map to global ids ----------------
__global__ void k_knn_merge(const float* __restrict__ pval, const int* __restrict__ pidx,
                            const int* __restrict__ grp, int* __restrict__ nbr)
{
    int t = blockIdx.x * 256 + threadIdx.x;
    if (t >= NGRP * GSZ) return;
    int g = t >> 11;
    float v0 = 1e30f, v1 = 1e30f, v2 = 1e30f;
    int   p0 = 0, p1 = 0, p2 = 0;
    const float* pv = pval + (size_t)t * 24;
    const int*   pi = pidx + (size_t)t * 24;
    for (int r = 0; r < 24; r++) ins3(pv[r], pi[r], v0, v1, v2, p0, p1, p2);
    int qi = grp[t];
    nbr[(size_t)qi * 3 + 0] = grp[g * GSZ + p0];
    nbr[(size_t)qi * 3 + 1] = grp[g * GSZ + p1];
    nbr[(size_t)qi * 3 + 2] = grp[g * GSZ + p2];
}

// ---------------- fused trunk MLP ----------------
// hT layout: rows 0..255 = h (transposed), rows 256..318 = xyz (transposed)
template<int MODE>   // 0: K rows from h; 1: K rows from xyz; 2: skip (xyz then h)
__device__ __forceinline__ void trunk_layer(float (*hT)[HPAD], float (*wbuf)[256],
        const float* __restrict__ W, const float* __restrict__ bias,
        int K, int do_relu, float* __restrict__ gout, int row0)
{
    const int tid = threadIdx.x;
    const int tx = tid & 31, ty = tid >> 5;
    const int c0 = tx * 8, r0 = ty * 8;
    float acc[8][8];
    #pragma unroll
    for (int i = 0; i < 8; i++)
        #pragma unroll
        for (int j = 0; j < 8; j++) acc[i][j] = 0.f;

    for (int k0 = 0; k0 < K; k0 += 32) {
        const int kc = (K - k0 < 32) ? (K - k0) : 32;
        __syncthreads();
        for (int s = tid; s < (kc << 8); s += 256) {
            int kk = s >> 8, c = s & 255;
            wbuf[kk][c] = W[(size_t)(k0 + kk) * 256 + c];
        }
        __syncthreads();
        for (int kk = 0; kk < kc; kk++) {
            const int k = k0 + kk;
            int lr;
            if (MODE == 0) lr = k;
            else if (MODE == 1) lr = 256 + k;
            else lr = (k < 63) ? (256 + k) : (k - 63);
            float4 a0 = *(const float4*)&hT[lr][r0];
            float4 a1 = *(const float4*)&hT[lr][r0 + 4];
            float4 w0v = *(const float4*)&wbuf[kk][c0];
            float4 w1v = *(const float4*)&wbuf[kk][c0 + 4];
            float av[8] = {a0.x,a0.y,a0.z,a0.w,a1.x,a1.y,a1.z,a1.w};
            float bv[8] = {w0v.x,w0v.y,w0v.z,w0v.w,w1v.x,w1v.y,w1v.z,w1v.w};
            #pragma unroll
            for (int i = 0; i < 8; i++)
                #pragma unroll
                for (int j = 0; j < 8; j++)
                    acc[i][j] = fmaf(av[i], bv[j], acc[i][j]);
        }
    }
    float bb[8];
    #pragma unroll
    for (int j = 0; j < 8; j++) bb[j] = bias[c0 + j];
    #pragma unroll
    for (int i = 0; i < 8; i++)
        #pragma unroll
        for (int j = 0; j < 8; j++) {
            float v = acc[i][j] + bb[j];
            acc[i][j] = do_relu ? fmaxf(v, 0.f) : v;
        }
    __syncthreads();   // all reads of old hT complete before overwrite
    if (gout) {
        #pragma unroll
        for (int i = 0; i < 8; i++) {
            float4 lo = make_float4(acc[i][0], acc[i][1], acc[i][2], acc[i][3]);
            float4 hi = make_float4(acc[i][4], acc[i][5], acc[i][6], acc[i][7]);
            *(float4*)&gout[(size_t)(row0 + r0 + i) * 256 + c0]     = lo;
            *(float4*)&gout[(size_t)(row0 + r0 + i) * 256 + c0 + 4] = hi;
        }
    } else {
        #pragma unroll
        for (int j = 0; j < 8; j++) {
            float4 lo = make_float4(acc[0][j], acc[1][j], acc[2][j], acc[3][j]);
            float4 hi = make_float4(acc[4][j], acc[5][j], acc[6][j], acc[7][j]);
            *(float4*)&hT[c0 + j][r0]     = lo;
            *(float4*)&hT[c0 + j][r0 + 4] = hi;
        }
    }
}

__global__ __launch_bounds__(256) void k_trunk(const float* __restrict__ x,
    const float* __restrict__ w0, const float* __restrict__ b0,
    const float* __restrict__ wmid, const float* __restrict__ bmid,
    const float* __restrict__ wskip, const float* __restrict__ bskip,
    const float* __restrict__ wfin, const float* __restrict__ bfin,
    const float* __restrict__ wsig, const float* __restrict__ bsig,
    float* __restrict__ feat, float* __restrict__ out)
{
    __shared__ float hT[319][HPAD];
    __shared__ float wbuf[32][256];
    const int tid = threadIdx.x;
    const int row0 = blockIdx.x * 64;
    for (int s = tid; s < 63 * 64; s += 256) {
        int k = s >> 6, r = s & 63;
        hT[256 + k][r] = x[(size_t)(row0 + r) * 90 + k];
    }
    trunk_layer<1>(hT, wbuf, w0, b0, 63, 1, nullptr, row0);
    trunk_layer<0>(hT, wbuf, wmid + 0*65536, bmid + 0*256, 256, 1, nullptr, row0);
    trunk_layer<0>(hT, wbuf, wmid + 1*65536, bmid + 1*256, 256, 1, nullptr, row0);
    trunk_layer<0>(hT, wbuf, wmid + 2*65536, bmid + 2*256, 256, 1, nullptr, row0);
    trunk_layer<2>(hT, wbuf, wskip, bskip, 319, 1, nullptr, row0);
    trunk_layer<0>(hT, wbuf, wmid + 3*65536, bmid + 3*256, 256, 1, nullptr, row0);
    trunk_layer<0>(hT, wbuf, wmid + 4*65536, bmid + 4*256, 256, 1, nullptr, row0);
    trunk_layer<0>(hT, wbuf, wmid + 5*65536, bmid + 5*256, 256, 1, nullptr, row0);
    trunk_layer<0>(hT, wbuf, wfin, bfin, 256, 0, feat, row0);   // feat, no relu
    __syncthreads();
    if (tid < 64) {   // sigma from final h (still in hT)
        float s = bsig[0];
        for (int k = 0; k < 256; k++) s = fmaf(hT[k][tid], wsig[k], s);
        out[(size_t)(row0 + tid) * 4 + 3] = s;
    }
}

// ---------------- PQ GEMMs for edge convs ----------------
// PQ1: Xe=[feat(256), dir(27)] (K=283); cols 0..127 = Xe@W_top, 128..255 = Xe@W_bot
__global__ __launch_bounds__(256) void k_pq1(const float* __restrict__ feat,
    const float* __restrict__ x, const float* __restrict__ ew1,
    float* __restrict__ PQ)
{
    __shared__ float aT[283][HPAD];
    __shared__ float wbuf[32][256];
    const int tid = threadIdx.x;
    const int tx = tid & 31, ty = tid >> 5;
    const int c0 = tx * 8, r0 = ty * 8;
    const int row0 = blockIdx.x * 64;
    for (int s = tid; s < 64 * 256; s += 256) {
        int r = s >> 8, k = s & 255;
        aT[k][r] = feat[(size_t)(row0 + r) * 256 + k];
    }
    for (int s = tid; s < 27 * 64; s += 256) {
        int dd = s >> 6, r = s & 63;
        aT[256 + dd][r] = x[(size_t)(row0 + r) * 90 + 63 + dd];
    }
    float acc[8][8];
    #pragma unroll
    for (int i = 0; i < 8; i++)
        #pragma unroll
        for (int j = 0; j < 8; j++) acc[i][j] = 0.f;
    for (int k0 = 0; k0 < 283; k0 += 32) {
        const int kc = (283 - k0 < 32) ? (283 - k0) : 32;
        __syncthreads();
        for (int s = tid; s < (kc << 8); s += 256) {
            int kk = s >> 8, c = s & 255;
            int k = k0 + kk;
            wbuf[kk][c] = (c < 128) ? ew1[(size_t)k * 128 + c]
                                    : ew1[(size_t)(283 + k) * 128 + (c - 128)];
        }
        __syncthreads();
        for (int kk = 0; kk < kc; kk++) {
            const int k = k0 + kk;
            float4 a0 = *(const float4*)&aT[k][r0];
            float4 a1 = *(const float4*)&aT[k][r0 + 4];
            float4 w0v = *(const float4*)&wbuf[kk][c0];
            float4 w1v = *(const float4*)&wbuf[kk][c0 + 4];
            float av[8] = {a0.x,a0.y,a0.z,a0.w,a1.x,a1.y,a1.z,a1.w};
            float bv[8] = {w0v.x,w0v.y,w0v.z,w0v.w,w1v.x,w1v.y,w1v.z,w1v.w};
            #pragma unroll
            for (int i = 0; i < 8; i++)
                #pragma unroll
                for (int j = 0; j < 8; j++)
                    acc[i][j] = fmaf(av[i], bv[j], acc[i][j]);
        }
    }
    #pragma unroll
    for (int i = 0; i < 8; i++) {
        float4 lo = make_float4(acc[i][0], acc[i][1], acc[i][2], acc[i][3]);
        float4 hi = make_float4(acc[i][4], acc[i][5], acc[i][6], acc[i][7]);
        *(float4*)&PQ[(size_t)(row0 + r0 + i) * 256 + c0]     = lo;
        *(float4*)&PQ[(size_t)(row0 + r0 + i) * 256 + c0 + 4] = hi;
    }
}

// PQ2: input d1 (K=128)
__global__ __launch_bounds__(256) void k_pq2(const float* __restrict__ d1,
    const float* __restrict__ ew1, float* __restrict__ PQ)
{
    __shared__ float aT[128][HPAD];
    __shared__ float wbuf[32][256];
    const int tid = threadIdx.x;
    const int tx = tid & 31, ty = tid >> 5;
    const int c0 = tx * 8, r0 = ty * 8;
    const int row0 = blockIdx.x * 64;
    for (int s = tid; s < 64 * 128; s += 256) {
        int r = s >> 7, k = s & 127;
        aT[k][r] = d1[(size_t)(row0 + r) * 128 + k];
    }
    float acc[8][8];
    #pragma unroll
    for (int i = 0; i < 8; i++)
        #pragma unroll
        for (int j = 0; j < 8; j++) acc[i][j] = 0.f;
    for (int k0 = 0; k0 < 128; k0 += 32) {
        __syncthreads();
        for (int s = tid; s < 32 * 256; s += 256) {
            int kk = s >> 8, c = s & 255;
            int k = k0 + kk;
            wbuf[kk][c] = (c < 128) ? ew1[(size_t)k * 128 + c]
                                    : ew1[(size_t)(128 + k) * 128 + (c - 128)];
        }
        __syncthreads();
        for (int kk = 0; kk < 32; kk++) {
            const int k = k0 + kk;
            float4 a0 = *(const float4*)&aT[k][r0];
            float4 a1 = *(const float4*)&aT[k][r0 + 4];
            float4 w0v = *(const float4*)&wbuf[kk][c0];
            float4 w1v = *(const float4*)&wbuf[kk][c0 + 4];
            float av[8] = {a0.x,a0.y,a0.z,a0.w,a1.x,a1.y,a1.z,a1.w};
            float bv[8] = {w0v.x,w0v.y,w0v.z,w0v.w,w1v.x,w1v.y,w1v.z,w1v.w};
            #pragma unroll
            for (int i = 0; i < 8; i++)
                #pragma unroll
                for (int j = 0; j < 8; j++)
                    acc[i][j] = fmaf(av[i], bv[j], acc[i][j]);
        }
    }
    #pragma unroll
    for (int i = 0; i < 8; i++) {
        float4 lo = make_float4(acc[i][0], acc[i][1], acc[i][2], acc[i][3]);
        float4 hi = make_float4(acc[i][4], acc[i][5], acc[i][6], acc[i][7]);
        *(float4*)&PQ[(size_t)(row0 + r0 + i) * 256 + c0]     = lo;
        *(float4*)&PQ[(size_t)(row0 + r0 + i) * 256 + c0 + 4] = hi;
    }
}

// ---------------- edge conv (h1 = relu(P_i + Q_j - Q_i + b1); h2 = relu(h1@w2+b2); mean) ----------------
template<int RGB>
__global__ __launch_bounds__(256) void k_edge(const float* __restrict__ PQ,
    const float* __restrict__ b1, const float* __restrict__ w2,
    const float* __restrict__ b2, const int* __restrict__ nbr,
    float* __restrict__ dout,
    const float* __restrict__ wrgb, const float* __restrict__ brgb,
    float* __restrict__ out)
{
    __shared__ float h1T[128][97];   // [col][edge], stride 97 => conflict-free
    __shared__ float wb[32][128];
    const int tid = threadIdx.x;
    const int n0 = blockIdx.x * 32;
    {
        const int c = tid & 127, eg = tid >> 7;
        const float bias = b1[c];
        for (int e = eg; e < 96; e += 2) {
            int n = e / 3;
            int jj = e - n * 3;
            int i = n0 + n;
            int j = nbr[(size_t)i * 3 + jj];
            float v = PQ[(size_t)i * 256 + c] + bias
                    + PQ[(size_t)j * 256 + 128 + c] - PQ[(size_t)i * 256 + 128 + c];
            h1T[c][e] = fmaxf(v, 0.f);
        }
    }
    const int cg = tid & 15, rg = tid >> 4;
    const int c0 = cg * 8, e0 = rg * 6;
    float acc[6][8];
    #pragma unroll
    for (int m = 0; m < 6; m++)
        #pragma unroll
        for (int j = 0; j < 8; j++) acc[m][j] = 0.f;
    for (int k0 = 0; k0 < 128; k0 += 32) {
        __syncthreads();
        for (int s = tid; s < 32 * 128; s += 256) {
            int kk = s >> 7, c = s & 127;
            wb[kk][c] = w2[(size_t)(k0 + kk) * 128 + c];
        }
        __syncthreads();
        for (int kk = 0; kk < 32; kk++) {
            const int k = k0 + kk;
            float av[6];
            #pragma unroll
            for (int m = 0; m < 6; m++) av[m] = h1T[k][e0 + m];
            float4 w0v = *(const float4*)&wb[kk][c0];
            float4 w1v = *(const float4*)&wb[kk][c0 + 4];
            float bv[8] = {w0v.x,w0v.y,w0v.z,w0v.w,w1v.x,w1v.y,w1v.z,w1v.w};
            #pragma unroll
            for (int m = 0; m < 6; m++)
                #pragma unroll
                for (int j = 0; j < 8; j++)
                    acc[m][j] = fmaf(av[m], bv[j], acc[m][j]);
        }
    }
    float bb[8];
    #pragma unroll
    for (int j = 0; j < 8; j++) bb[j] = b2[c0 + j];
    float dA[8], dB[8];
    #pragma unroll
    for (int j = 0; j < 8; j++) {
        float h0 = fmaxf(acc[0][j] + bb[j], 0.f);
        float h1 = fmaxf(acc[1][j] + bb[j], 0.f);
        float h2 = fmaxf(acc[2][j] + bb[j], 0.f);
        float h3 = fmaxf(acc[3][j] + bb[j], 0.f);
        float h4 = fmaxf(acc[4][j] + bb[j], 0.f);
        float h5 = fmaxf(acc[5][j] + bb[j], 0.f);
        dA[j] = (h0 + h1 + h2) * (1.f / 3.f);
        dB[j] = (h3 + h4 + h5) * (1.f / 3.f);
    }
    if (!RGB) {
        float4 lo, hi;
        lo = make_float4(dA[0], dA[1], dA[2], dA[3]);
        hi = make_float4(dA[4], dA[5], dA[6], dA[7]);
        *(float4*)&dout[(size_t)(n0 + 2*rg) * 128 + c0]     = lo;
        *(float4*)&dout[(size_t)(n0 + 2*rg) * 128 + c0 + 4] = hi;
        lo = make_float4(dB[0], dB[1], dB[2], dB[3]);
        hi = make_float4(dB[4], dB[5], dB[6], dB[7]);
        *(float4*)&dout[(size_t)(n0 + 2*rg + 1) * 128 + c0]     = lo;
        *(float4*)&dout[(size_t)(n0 + 2*rg + 1) * 128 + c0 + 4] = hi;
    } else {
        __syncthreads();                 // done reading h1T; reuse as d2 tile
        float* d2L = &h1T[0][0];         // [32][130]
        #pragma unroll
        for (int j = 0; j < 8; j++) {
            d2L[(2*rg)     * 130 + c0 + j] = dA[j];
            d2L[(2*rg + 1) * 130 + c0 + j] = dB[j];
        }
        __syncthreads();
        if (tid < 96) {
            int n = tid / 3, ch = tid - 3 * (tid / 3);
            float s = brgb[ch];
            for (int k = 0; k < 128; k++) s = fmaf(d2L[n * 130 + k], wrgb[k * 3 + ch], s);
            out[(size_t)(n0 + n) * 4 + ch] = 1.f / (1.f + expf(-s));
        }
    }
}

// ---------------- launch ----------------
extern "C" void kernel_launch(void* const* d_in, const int* in_sizes, int n_in,
                              void* d_out, int out_size, void* d_ws, size_t ws_size,
                              hipStream_t stream)
{
    const float* x     = (const float*)d_in[0];
    const int*   bid   = (const int*)d_in[1];
    const float* w0    = (const float*)d_in[2];
    const float* b0    = (const float*)d_in[3];
    const float* wmid  = (const float*)d_in[4];
    const float* bmid  = (const float*)d_in[5];
    const float* wskip = (const float*)d_in[6];
    const float* bskip = (const float*)d_in[7];
    const float* wfin  = (const float*)d_in[8];
    const float* bfin  = (const float*)d_in[9];
    const float* wsig  = (const float*)d_in[10];
    const float* bsig  = (const float*)d_in[11];
    const float* e1w1  = (const float*)d_in[12];
    const float* e1b1  = (const float*)d_in[13];
    const float* e1w2  = (const float*)d_in[14];
    const float* e1b2  = (const float*)d_in[15];
    const float* e2w1  = (const float*)d_in[16];
    const float* e2b1  = (const float*)d_in[17];
    const float* e2w2  = (const float*)d_in[18];
    const float* e2b2  = (const float*)d_in[19];
    const float* wrgb  = (const float*)d_in[20];
    const float* brgb  = (const float*)d_in[21];
    float* out = (float*)d_out;

    char* ws = (char*)d_ws;
    int* cnt = (int*)ws;                                   // 20 ints
    int* grp = (int*)(ws + 256);                           // 20*2048 ints
    int* nbr = (int*)(ws + 256 + NGRP * GSZ * 4);          // 40960*3 ints
    float* bufA = (float*)(ws + (1 << 20));                // 40960*256 f32 (feat, later d1)
    float* bufB = bufA + (size_t)B_TOTAL * 256;            // 40960*256 f32 (PQ1, later PQ2)

    // kNN scratch overlays (dead before trunk/pq writes):
    float* xgT   = bufA;                                   // 20*63*2048 f32 = 10.1 MB
    float* norms = bufA + (size_t)NGRP * 63 * GSZ;         // 40960 f32
    float* pval  = bufB;                                   // 20*2048*8*3 f32 = 3.9 MB
    int*   pidx  = (int*)(bufB + (size_t)NGRP * GSZ * 24); // same size

    hipMemsetAsync(cnt, 0, 256, stream);
    k_scatter<<<B_TOTAL / 256, 256, 0, stream>>>(bid, grp, cnt);
    k_gather<<<dim3(GSZ / 128, NGRP), 256, 0, stream>>>(x, grp, xgT, norms);
    k_knn_gemm<<<dim3(GSZ / 256, GSZ / 64, NGRP), 256, 0, stream>>>(xgT, norms, pval, pidx);
    k_knn_merge<<<(NGRP * GSZ + 255) / 256, 256, 0, stream>>>(pval, pidx, grp, nbr);
    k_trunk<<<B_TOTAL / 64, 256, 0, stream>>>(x, w0, b0, wmid, bmid, wskip, bskip,
                                              wfin, bfin, wsig, bsig, bufA, out);
    k_pq1<<<B_TOTAL / 64, 256, 0, stream>>>(bufA, x, e1w1, bufB);
    k_edge<0><<<B_TOTAL / 32, 256, 0, stream>>>(bufB, e1b1, e1w2, e1b2, nbr, bufA,
                                                nullptr, nullptr, nullptr);
    k_pq2<<<B_TOTAL / 64, 256, 0, stream>>>(bufA, e2w1, bufB);
    k_edge<1><<<B_TOTAL / 32, 256, 0, stream>>>(bufB, e2b1, e2w2, e2b2, nbr, nullptr,
                                                wrgb, brgb, out);
}

// Round 3
// 3202.051 us; speedup vs baseline: 1.0615x; 1.0615x over previous
//
#include <hip/hip_runtime.h>
#include <hip/hip_bf16.h>
#include <math.h>

#define B_TOTAL 40960
#define NGRP 20
#define GSZ 2048
#define HPAD 68   // LDS row stride (floats) for transposed activation tiles

// ---------------- group scatter ----------------
__global__ void k_scatter(const int* __restrict__ bid, int* __restrict__ grp,
                          int* __restrict__ cnt)
{
    int i = blockIdx.x * 256 + threadIdx.x;
    if (i < B_TOTAL) {
        int g = bid[i];
        int p = atomicAdd(&cnt[g], 1);
        grp[g * GSZ + p] = i;
    }
}

// ---------------- kNN stage 1: gather coords transposed + norms ----------------
__global__ __launch_bounds__(256) void k_gather(const float* __restrict__ x,
    const int* __restrict__ grp, float* __restrict__ xgT, float* __restrict__ norms)
{
    __shared__ float tile[128][65];
    __shared__ int ids[128];
    const int tid = threadIdx.x;
    const int g = blockIdx.y;
    const int q0 = blockIdx.x * 128;
    if (tid < 128) ids[tid] = grp[g * GSZ + q0 + tid];
    __syncthreads();
    for (int s = tid; s < 128 * 64; s += 256) {
        int q = s >> 6, d = s & 63;
        tile[q][d] = (d < 63) ? x[(size_t)ids[q] * 90 + d] : 0.f;
    }
    __syncthreads();
    if (tid < 128) {
        float a = 0.f;
        #pragma unroll
        for (int d = 0; d < 63; d++) a = fmaf(tile[tid][d], tile[tid][d], a);
        norms[g * GSZ + q0 + tid] = a;
    }
    for (int s = tid; s < 63 * 128; s += 256) {
        int d = s >> 7, q = s & 127;
        xgT[((size_t)g * 63 + d) * GSZ + q0 + q] = tile[q][d];
    }
}

// ---------------- helpers ----------------
__device__ __forceinline__ void ins3(float d, int p,
    float& v0, float& v1, float& v2, int& p0, int& p1, int& p2)
{
    if (d < v0)      { v2 = v1; p2 = p1; v1 = v0; p1 = p0; v0 = d; p0 = p; }
    else if (d < v1) { v2 = v1; p2 = p1; v1 = d;  p1 = p; }
    else if (d < v2) { v2 = d;  p2 = p; }
}

__device__ __forceinline__ void fma88(float acc[8][8], float4 a0, float4 a1,
                                      float4 b0, float4 b1)
{
    float av[8] = {a0.x,a0.y,a0.z,a0.w,a1.x,a1.y,a1.z,a1.w};
    float bv[8] = {b0.x,b0.y,b0.z,b0.w,b1.x,b1.y,b1.z,b1.w};
    #pragma unroll
    for (int i = 0; i < 8; i++)
        #pragma unroll
        for (int j = 0; j < 8; j++)
            acc[i][j] = fmaf(av[i], bv[j], acc[i][j]);
}

// stage one [16][256] chunk into registers (rows >= K zero-padded)
__device__ __forceinline__ void stage_w256(const float* __restrict__ W, int k0, int K,
                                           float4 st[4], int tid)
{
    #pragma unroll
    for (int u = 0; u < 4; u++) {
        int f = tid + (u << 8);
        int kk = f >> 6, c4 = (f & 63) << 2;
        int k = k0 + kk;
        st[u] = (k < K) ? *(const float4*)&W[(size_t)k * 256 + c4]
                        : make_float4(0.f, 0.f, 0.f, 0.f);
    }
}

// stage for edge-conv PQ weights: cols 0..127 from top half, 128..255 from bottom half
__device__ __forceinline__ void stage_wpq(const float* __restrict__ ew1, int k0, int K,
                                          float4 st[4], int tid)
{
    #pragma unroll
    for (int u = 0; u < 4; u++) {
        int f = tid + (u << 8);
        int kk = f >> 6, c4 = (f & 63) << 2;
        int k = k0 + kk;
        if (k >= K) st[u] = make_float4(0.f, 0.f, 0.f, 0.f);
        else st[u] = (c4 < 128) ? *(const float4*)&ew1[(size_t)k * 128 + c4]
                                : *(const float4*)&ew1[(size_t)(K + k) * 128 + (c4 - 128)];
    }
}

__device__ __forceinline__ void stage_knnB(const float* __restrict__ base, int k0, int c0,
                                           float4 st[4], int tid)
{
    #pragma unroll
    for (int u = 0; u < 4; u++) {
        int f = tid + (u << 8);
        int kk = f >> 6, c4 = (f & 63) << 2;
        int k = k0 + kk;
        st[u] = (k < 63) ? *(const float4*)&base[(size_t)k * GSZ + c0 + c4]
                         : make_float4(0.f, 0.f, 0.f, 0.f);
    }
}

__device__ __forceinline__ void stage_write(float (*buf)[256], const float4 st[4], int tid)
{
    #pragma unroll
    for (int u = 0; u < 4; u++) {
        int f = tid + (u << 8);
        int kk = f >> 6, c4 = (f & 63) << 2;
        *(float4*)&buf[kk][c4] = st[u];
    }
}

// ---------------- kNN stage 2: tiled distance GEMM + partial top3 ----------------
// grid: (cand tile 0..7, query tile 0..31, group 0..19)
__global__ __launch_bounds__(256) void k_knn_gemm(const float* __restrict__ xgT,
    const float* __restrict__ norms, float* __restrict__ pval, int* __restrict__ pidx)
{
    __shared__ float aT[64][72];        // queries^T (row 63 zeroed)
    __shared__ float bb[2][16][256];    // candidate k-chunks, double-buffered
    __shared__ float qnS[64];
    __shared__ float cnS[256];
    const int tid = threadIdx.x;
    const int tx = tid & 31, ty = tid >> 5;
    const int cLo = tx * 4, cHi = 128 + tx * 4, r0 = ty * 8;
    const int g = blockIdx.z;
    const int q0 = blockIdx.y * 64;
    const int c0 = blockIdx.x * 256;
    const float* base = xgT + (size_t)g * 63 * GSZ;

    for (int s = tid; s < 64 * 16; s += 256) {
        int d = s >> 4, q4 = (s & 15) << 2;
        *(float4*)&aT[d][q4] = (d < 63) ? *(const float4*)&base[(size_t)d * GSZ + q0 + q4]
                                        : make_float4(0.f, 0.f, 0.f, 0.f);
    }
    if (tid < 64) qnS[tid] = norms[g * GSZ + q0 + tid];
    cnS[tid] = norms[g * GSZ + c0 + tid];

    float4 st[4];
    stage_knnB(base, 0, c0, st, tid);
    __syncthreads();
    stage_write(bb[0], st, tid);
    __syncthreads();

    float acc[8][8];
    #pragma unroll
    for (int i = 0; i < 8; i++)
        #pragma unroll
        for (int j = 0; j < 8; j++) acc[i][j] = 0.f;

    for (int c = 0; c < 4; c++) {
        const int cur = c & 1;
        const bool more = (c < 3);
        if (more) stage_knnB(base, (c + 1) << 4, c0, st, tid);
        const float (*bbc)[256] = bb[cur];
        #pragma unroll
        for (int kk = 0; kk < 16; kk++) {
            const int k = (c << 4) + kk;
            float4 a0 = *(const float4*)&aT[k][r0];
            float4 a1 = *(const float4*)&aT[k][r0 + 4];
            float4 b0 = *(const float4*)&bbc[kk][cLo];
            float4 b1 = *(const float4*)&bbc[kk][cHi];
            fma88(acc, a0, a1, b0, b1);
        }
        if (more) stage_write(bb[cur ^ 1], st, tid);
        __syncthreads();
    }

    #pragma unroll
    for (int i = 0; i < 8; i++) {
        const int qpos = q0 + r0 + i;
        const float qn = qnS[r0 + i];
        float v0 = 1e30f, v1 = 1e30f, v2 = 1e30f;
        int   p0 = 0, p1 = 0, p2 = 0;
        #pragma unroll
        for (int j = 0; j < 8; j++) {
            int cl = (j < 4) ? (cLo + j) : (cHi + j - 4);
            int cpos = c0 + cl;
            float d2 = qn + cnS[cl] - 2.f * acc[i][j];
            if (cpos != qpos) ins3(d2, cpos, v0, v1, v2, p0, p1, p2);
        }
        #pragma unroll
        for (int m = 1; m <= 16; m <<= 1) {
            float o0 = __shfl_xor(v0, m), o1 = __shfl_xor(v1, m), o2 = __shfl_xor(v2, m);
            int   q0_ = __shfl_xor(p0, m), q1_ = __shfl_xor(p1, m), q2_ = __shfl_xor(p2, m);
            ins3(o0, q0_, v0, v1, v2, p0, p1, p2);
            ins3(o1, q1_, v0, v1, v2, p0, p1, p2);
            ins3(o2, q2_, v0, v1, v2, p0, p1, p2);
        }
        if (tx == 0) {
            size_t off = (((size_t)g * GSZ + qpos) * 8 + blockIdx.x) * 3;
            pval[off + 0] = v0; pidx[off + 0] = p0;
            pval[off + 1] = v1; pidx[off + 1] = p1;
            pval[off + 2] = v2; pidx[off + 2] = p2;
        }
    }
}

// ---------------- kNN stage 3: merge 8 partials, map to global ids ----------------
__global__ void k_knn_merge(const float* __restrict__ pval, const int* __restrict__ pidx,
                            const int* __restrict__ grp, int* __restrict__ nbr)
{
    int t = blockIdx.x * 256 + threadIdx.x;
    if (t >= NGRP * GSZ) return;
    int g = t >> 11;
    float v0 = 1e30f, v1 = 1e30f, v2 = 1e30f;
    int   p0 = 0, p1 = 0, p2 = 0;
    const float* pv = pval + (size_t)t * 24;
    const int*   pi = pidx + (size_t)t * 24;
    for (int r = 0; r < 24; r++) ins3(pv[r], pi[r], v0, v1, v2, p0, p1, p2);
    int qi = grp[t];
    nbr[(size_t)qi * 3 + 0] = grp[g * GSZ + p0];
    nbr[(size_t)qi * 3 + 1] = grp[g * GSZ + p1];
    nbr[(size_t)qi * 3 + 2] = grp[g * GSZ + p2];
}

// ---------------- fused trunk MLP ----------------
// hT rows 0..255 = h^T, rows 256..318 = xyz^T, row 319 = zeros (pad)
template<int MODE>   // 0: K rows from h; 1: K rows from xyz; 2: skip (xyz then h)
__device__ __forceinline__ void trunk_layer(float (*hT)[HPAD], float (*wbuf)[16][256],
        const float* __restrict__ W, const float* __restrict__ bias,
        int K, int do_relu, float* __restrict__ gout, int row0)
{
    const int tid = threadIdx.x;
    const int tx = tid & 31, ty = tid >> 5;
    const int cLo = tx * 4, cHi = 128 + tx * 4, r0 = ty * 8;
    const int nch = (K + 15) >> 4;
    float acc[8][8];
    #pragma unroll
    for (int i = 0; i < 8; i++)
        #pragma unroll
        for (int j = 0; j < 8; j++) acc[i][j] = 0.f;

    float4 st[4];
    stage_w256(W, 0, K, st, tid);
    __syncthreads();                 // prev-layer hT writes done; wbuf free
    stage_write(wbuf[0], st, tid);
    __syncthreads();

    for (int c = 0; c < nch; c++) {
        const int cur = c & 1;
        const bool more = (c + 1 < nch);
        if (more) stage_w256(W, (c + 1) << 4, K, st, tid);
        const float (*wb)[256] = wbuf[cur];
        const int kbase = c << 4;
        #pragma unroll
        for (int kk = 0; kk < 16; kk++) {
            const int k = kbase + kk;
            int lr;
            if (MODE == 0) lr = k;
            else if (MODE == 1) lr = 256 + k;
            else lr = (k < 63) ? (256 + k) : (k - 63);
            float4 a0 = *(const float4*)&hT[lr][r0];
            float4 a1 = *(const float4*)&hT[lr][r0 + 4];
            float4 b0 = *(const float4*)&wb[kk][cLo];
            float4 b1 = *(const float4*)&wb[kk][cHi];
            fma88(acc, a0, a1, b0, b1);
        }
        if (more) stage_write(wbuf[cur ^ 1], st, tid);
        __syncthreads();
    }

    float bL[4], bH[4];
    #pragma unroll
    for (int j = 0; j < 4; j++) { bL[j] = bias[cLo + j]; bH[j] = bias[cHi + j]; }
    #pragma unroll
    for (int i = 0; i < 8; i++)
        #pragma unroll
        for (int j = 0; j < 8; j++) {
            float v = acc[i][j] + ((j < 4) ? bL[j] : bH[j - 4]);
            acc[i][j] = do_relu ? fmaxf(v, 0.f) : v;
        }
    if (gout) {
        #pragma unroll
        for (int i = 0; i < 8; i++) {
            *(float4*)&gout[(size_t)(row0 + r0 + i) * 256 + cLo] =
                make_float4(acc[i][0], acc[i][1], acc[i][2], acc[i][3]);
            *(float4*)&gout[(size_t)(row0 + r0 + i) * 256 + cHi] =
                make_float4(acc[i][4], acc[i][5], acc[i][6], acc[i][7]);
        }
    } else {
        #pragma unroll
        for (int j = 0; j < 4; j++) {
            *(float4*)&hT[cLo + j][r0]     = make_float4(acc[0][j], acc[1][j], acc[2][j], acc[3][j]);
            *(float4*)&hT[cLo + j][r0 + 4] = make_float4(acc[4][j], acc[5][j], acc[6][j], acc[7][j]);
            *(float4*)&hT[cHi + j][r0]     = make_float4(acc[0][j+4], acc[1][j+4], acc[2][j+4], acc[3][j+4]);
            *(float4*)&hT[cHi + j][r0 + 4] = make_float4(acc[4][j+4], acc[5][j+4], acc[6][j+4], acc[7][j+4]);
        }
    }
}

__global__ __launch_bounds__(256) void k_trunk(const float* __restrict__ x,
    const float* __restrict__ w0, const float* __restrict__ b0,
    const float* __restrict__ wmid, const float* __restrict__ bmid,
    const float* __restrict__ wskip, const float* __restrict__ bskip,
    const float* __restrict__ wfin, const float* __restrict__ bfin,
    const float* __restrict__ wsig, const float* __restrict__ bsig,
    float* __restrict__ feat, float* __restrict__ out)
{
    __shared__ float hT[320][HPAD];
    __shared__ float wbuf[2][16][256];
    const int tid = threadIdx.x;
    const int row0 = blockIdx.x * 64;
    for (int s = tid; s < 64 * 64; s += 256) {   // rows 256..319; 319 zeroed
        int k = s >> 6, r = s & 63;
        hT[256 + k][r] = (k < 63) ? x[(size_t)(row0 + r) * 90 + k] : 0.f;
    }
    trunk_layer<1>(hT, wbuf, w0, b0, 63, 1, nullptr, row0);
    trunk_layer<0>(hT, wbuf, wmid + 0*65536, bmid + 0*256, 256, 1, nullptr, row0);
    trunk_layer<0>(hT, wbuf, wmid + 1*65536, bmid + 1*256, 256, 1, nullptr, row0);
    trunk_layer<0>(hT, wbuf, wmid + 2*65536, bmid + 2*256, 256, 1, nullptr, row0);
    trunk_layer<2>(hT, wbuf, wskip, bskip, 319, 1, nullptr, row0);
    trunk_layer<0>(hT, wbuf, wmid + 3*65536, bmid + 3*256, 256, 1, nullptr, row0);
    trunk_layer<0>(hT, wbuf, wmid + 4*65536, bmid + 4*256, 256, 1, nullptr, row0);
    trunk_layer<0>(hT, wbuf, wmid + 5*65536, bmid + 5*256, 256, 1, nullptr, row0);
    trunk_layer<0>(hT, wbuf, wfin, bfin, 256, 0, feat, row0);   // feat, no relu
    __syncthreads();
    if (tid < 64) {   // sigma from final h (still in hT)
        float s = bsig[0];
        for (int k = 0; k < 256; k++) s = fmaf(hT[k][tid], wsig[k], s);
        out[(size_t)(row0 + tid) * 4 + 3] = s;
    }
}

// ---------------- PQ GEMMs for edge convs ----------------
// PQ1: Xe=[feat(256), dir(27)] (K=283); cols 0..127 = Xe@W_top, 128..255 = Xe@W_bot
__global__ __launch_bounds__(256) void k_pq1(const float* __restrict__ feat,
    const float* __restrict__ x, const float* __restrict__ ew1,
    float* __restrict__ PQ)
{
    __shared__ float aT[288][HPAD];     // rows 283..287 zeroed
    __shared__ float wbuf[2][16][256];
    const int tid = threadIdx.x;
    const int tx = tid & 31, ty = tid >> 5;
    const int cLo = tx * 4, cHi = 128 + tx * 4, r0 = ty * 8;
    const int row0 = blockIdx.x * 64;
    const int K = 283;
    for (int s = tid; s < 64 * 256; s += 256) {
        int r = s >> 8, k = s & 255;
        aT[k][r] = feat[(size_t)(row0 + r) * 256 + k];
    }
    for (int s = tid; s < 32 * 64; s += 256) {
        int dd = s >> 6, r = s & 63;
        aT[256 + dd][r] = (dd < 27) ? x[(size_t)(row0 + r) * 90 + 63 + dd] : 0.f;
    }
    float4 st[4];
    stage_wpq(ew1, 0, K, st, tid);
    __syncthreads();
    stage_write(wbuf[0], st, tid);
    __syncthreads();

    float acc[8][8];
    #pragma unroll
    for (int i = 0; i < 8; i++)
        #pragma unroll
        for (int j = 0; j < 8; j++) acc[i][j] = 0.f;

    const int nch = (K + 15) >> 4;   // 18
    for (int c = 0; c < nch; c++) {
        const int cur = c & 1;
        const bool more = (c + 1 < nch);
        if (more) stage_wpq(ew1, (c + 1) << 4, K, st, tid);
        const float (*wb)[256] = wbuf[cur];
        const int kbase = c << 4;
        #pragma unroll
        for (int kk = 0; kk < 16; kk++) {
            const int k = kbase + kk;
            float4 a0 = *(const float4*)&aT[k][r0];
            float4 a1 = *(const float4*)&aT[k][r0 + 4];
            float4 b0 = *(const float4*)&wb[kk][cLo];
            float4 b1 = *(const float4*)&wb[kk][cHi];
            fma88(acc, a0, a1, b0, b1);
        }
        if (more) stage_write(wbuf[cur ^ 1], st, tid);
        __syncthreads();
    }
    #pragma unroll
    for (int i = 0; i < 8; i++) {
        *(float4*)&PQ[(size_t)(row0 + r0 + i) * 256 + cLo] =
            make_float4(acc[i][0], acc[i][1], acc[i][2], acc[i][3]);
        *(float4*)&PQ[(size_t)(row0 + r0 + i) * 256 + cHi] =
            make_float4(acc[i][4], acc[i][5], acc[i][6], acc[i][7]);
    }
}

// PQ2: input d1 (K=128)
__global__ __launch_bounds__(256) void k_pq2(const float* __restrict__ d1,
    const float* __restrict__ ew1, float* __restrict__ PQ)
{
    __shared__ float aT[128][HPAD];
    __shared__ float wbuf[2][16][256];
    const int tid = threadIdx.x;
    const int tx = tid & 31, ty = tid >> 5;
    const int cLo = tx * 4, cHi = 128 + tx * 4, r0 = ty * 8;
    const int row0 = blockIdx.x * 64;
    const int K = 128;
    for (int s = tid; s < 64 * 128; s += 256) {
        int r = s >> 7, k = s & 127;
        aT[k][r] = d1[(size_t)(row0 + r) * 128 + k];
    }
    float4 st[4];
    stage_wpq(ew1, 0, K, st, tid);
    __syncthreads();
    stage_write(wbuf[0], st, tid);
    __syncthreads();

    float acc[8][8];
    #pragma unroll
    for (int i = 0; i < 8; i++)
        #pragma unroll
        for (int j = 0; j < 8; j++) acc[i][j] = 0.f;

    for (int c = 0; c < 8; c++) {
        const int cur = c & 1;
        const bool more = (c < 7);
        if (more) stage_wpq(ew1, (c + 1) << 4, K, st, tid);
        const float (*wb)[256] = wbuf[cur];
        const int kbase = c << 4;
        #pragma unroll
        for (int kk = 0; kk < 16; kk++) {
            const int k = kbase + kk;
            float4 a0 = *(const float4*)&aT[k][r0];
            float4 a1 = *(const float4*)&aT[k][r0 + 4];
            float4 b0 = *(const float4*)&wb[kk][cLo];
            float4 b1 = *(const float4*)&wb[kk][cHi];
            fma88(acc, a0, a1, b0, b1);
        }
        if (more) stage_write(wbuf[cur ^ 1], st, tid);
        __syncthreads();
    }
    #pragma unroll
    for (int i = 0; i < 8; i++) {
        *(float4*)&PQ[(size_t)(row0 + r0 + i) * 256 + cLo] =
            make_float4(acc[i][0], acc[i][1], acc[i][2], acc[i][3]);
        *(float4*)&PQ[(size_t)(row0 + r0 + i) * 256 + cHi] =
            make_float4(acc[i][4], acc[i][5], acc[i][6], acc[i][7]);
    }
}

// ---------------- edge conv (h1 = relu(P_i + Q_j - Q_i + b1); h2 = relu(h1@w2+b2); mean) ----------------
template<int RGB>
__global__ __launch_bounds__(256) void k_edge(const float* __restrict__ PQ,
    const float* __restrict__ b1, const float* __restrict__ w2,
    const float* __restrict__ b2, const int* __restrict__ nbr,
    float* __restrict__ dout,
    const float* __restrict__ wrgb, const float* __restrict__ brgb,
    float* __restrict__ out)
{
    __shared__ float h1T[128][97];   // [col][edge]
    __shared__ float wb[32][128];
    const int tid = threadIdx.x;
    const int n0 = blockIdx.x * 32;
    {
        const int c = tid & 127, eg = tid >> 7;
        const float bias = b1[c];
        for (int e = eg; e < 96; e += 2) {
            int n = e / 3;
            int jj = e - n * 3;
            int i = n0 + n;
            int j = nbr[(size_t)i * 3 + jj];
            float v = PQ[(size_t)i * 256 + c] + bias
                    + PQ[(size_t)j * 256 + 128 + c] - PQ[(size_t)i * 256 + 128 + c];
            h1T[c][e] = fmaxf(v, 0.f);
        }
    }
    const int cg = tid & 15, rg = tid >> 4;
    const int cLo = cg * 4, cHi = 64 + cg * 4, e0 = rg * 6;
    float acc[6][8];
    #pragma unroll
    for (int m = 0; m < 6; m++)
        #pragma unroll
        for (int j = 0; j < 8; j++) acc[m][j] = 0.f;
    for (int k0 = 0; k0 < 128; k0 += 32) {
        __syncthreads();
        for (int s = tid; s < 32 * 128; s += 256) {
            int kk = s >> 7, c = s & 127;
            wb[kk][c] = w2[(size_t)(k0 + kk) * 128 + c];
        }
        __syncthreads();
        for (int kk = 0; kk < 32; kk++) {
            const int k = k0 + kk;
            float av[6];
            #pragma unroll
            for (int m = 0; m < 6; m++) av[m] = h1T[k][e0 + m];
            float4 w0v = *(const float4*)&wb[kk][cLo];
            float4 w1v = *(const float4*)&wb[kk][cHi];
            float bv[8] = {w0v.x,w0v.y,w0v.z,w0v.w,w1v.x,w1v.y,w1v.z,w1v.w};
            #pragma unroll
            for (int m = 0; m < 6; m++)
                #pragma unroll
                for (int j = 0; j < 8; j++)
                    acc[m][j] = fmaf(av[m], bv[j], acc[m][j]);
        }
    }
    float bb[8];
    #pragma unroll
    for (int j = 0; j < 8; j++) bb[j] = b2[(j < 4) ? (cLo + j) : (cHi + j - 4)];
    float dA[8], dB[8];
    #pragma unroll
    for (int j = 0; j < 8; j++) {
        float h0 = fmaxf(acc[0][j] + bb[j], 0.f);
        float h1 = fmaxf(acc[1][j] + bb[j], 0.f);
        float h2 = fmaxf(acc[2][j] + bb[j], 0.f);
        float h3 = fmaxf(acc[3][j] + bb[j], 0.f);
        float h4 = fmaxf(acc[4][j] + bb[j], 0.f);
        float h5 = fmaxf(acc[5][j] + bb[j], 0.f);
        dA[j] = (h0 + h1 + h2) * (1.f / 3.f);
        dB[j] = (h3 + h4 + h5) * (1.f / 3.f);
    }
    if (!RGB) {
        *(float4*)&dout[(size_t)(n0 + 2*rg) * 128 + cLo] = make_float4(dA[0], dA[1], dA[2], dA[3]);
        *(float4*)&dout[(size_t)(n0 + 2*rg) * 128 + cHi] = make_float4(dA[4], dA[5], dA[6], dA[7]);
        *(float4*)&dout[(size_t)(n0 + 2*rg + 1) * 128 + cLo] = make_float4(dB[0], dB[1], dB[2], dB[3]);
        *(float4*)&dout[(size_t)(n0 + 2*rg + 1) * 128 + cHi] = make_float4(dB[4], dB[5], dB[6], dB[7]);
    } else {
        __syncthreads();                 // done reading h1T; reuse as d2 tile
        float* d2L = &h1T[0][0];         // [32][130]
        #pragma unroll
        for (int j = 0; j < 4; j++) {
            d2L[(2*rg)     * 130 + cLo + j] = dA[j];
            d2L[(2*rg)     * 130 + cHi + j] = dA[j + 4];
            d2L[(2*rg + 1) * 130 + cLo + j] = dB[j];
            d2L[(2*rg + 1) * 130 + cHi + j] = dB[j + 4];
        }
        __syncthreads();
        if (tid < 96) {
            int n = tid / 3, ch = tid - 3 * (tid / 3);
            float s = brgb[ch];
            for (int k = 0; k < 128; k++) s = fmaf(d2L[n * 130 + k], wrgb[k * 3 + ch], s);
            out[(size_t)(n0 + n) * 4 + ch] = 1.f / (1.f + expf(-s));
        }
    }
}

// ---------------- launch ----------------
extern "C" void kernel_launch(void* const* d_in, const int* in_sizes, int n_in,
                              void* d_out, int out_size, void* d_ws, size_t ws_size,
                              hipStream_t stream)
{
    const float* x     = (const float*)d_in[0];
    const int*   bid   = (const int*)d_in[1];
    const float* w0    = (const float*)d_in[2];
    const float* b0    = (const float*)d_in[3];
    const float* wmid  = (const float*)d_in[4];
    const float* bmid  = (const float*)d_in[5];
    const float* wskip = (const float*)d_in[6];
    const float* bskip = (const float*)d_in[7];
    const float* wfin  = (const float*)d_in[8];
    const float* bfin  = (const float*)d_in[9];
    const float* wsig  = (const float*)d_in[10];
    const float* bsig  = (const float*)d_in[11];
    const float* e1w1  = (const float*)d_in[12];
    const float* e1b1  = (const float*)d_in[13];
    const float* e1w2  = (const float*)d_in[14];
    const float* e1b2  = (const float*)d_in[15];
    const float* e2w1  = (const float*)d_in[16];
    const float* e2b1  = (const float*)d_in[17];
    const float* e2w2  = (const float*)d_in[18];
    const float* e2b2  = (const float*)d_in[19];
    const float* wrgb  = (const float*)d_in[20];
    const float* brgb  = (const float*)d_in[21];
    float* out = (float*)d_out;

    char* ws = (char*)d_ws;
    int* cnt = (int*)ws;                                   // 20 ints
    int* grp = (int*)(ws + 256);                           // 20*2048 ints
    int* nbr = (int*)(ws + 256 + NGRP * GSZ * 4);          // 40960*3 ints
    float* bufA = (float*)(ws + (1 << 20));                // 40960*256 f32 (feat, later d1)
    float* bufB = bufA + (size_t)B_TOTAL * 256;            // 40960*256 f32 (PQ1, later PQ2)

    // kNN scratch overlays (dead before trunk/pq writes):
    float* xgT   = bufA;                                   // 20*63*2048 f32 = 10.1 MB
    float* norms = bufA + (size_t)NGRP * 63 * GSZ;         // 40960 f32
    float* pval  = bufB;                                   // 20*2048*8*3 f32 = 3.9 MB
    int*   pidx  = (int*)(bufB + (size_t)NGRP * GSZ * 24); // same size

    hipMemsetAsync(cnt, 0, 256, stream);
    k_scatter<<<B_TOTAL / 256, 256, 0, stream>>>(bid, grp, cnt);
    k_gather<<<dim3(GSZ / 128, NGRP), 256, 0, stream>>>(x, grp, xgT, norms);
    k_knn_gemm<<<dim3(GSZ / 256, GSZ / 64, NGRP), 256, 0, stream>>>(xgT, norms, pval, pidx);
    k_knn_merge<<<(NGRP * GSZ + 255) / 256, 256, 0, stream>>>(pval, pidx, grp, nbr);
    k_trunk<<<B_TOTAL / 64, 256, 0, stream>>>(x, w0, b0, wmid, bmid, wskip, bskip,
                                              wfin, bfin, wsig, bsig, bufA, out);
    k_pq1<<<B_TOTAL / 64, 256, 0, stream>>>(bufA, x, e1w1, bufB);
    k_edge<0><<<B_TOTAL / 32, 256, 0, stream>>>(bufB, e1b1, e1w2, e1b2, nbr, bufA,
                                                nullptr, nullptr, nullptr);
    k_pq2<<<B_TOTAL / 64, 256, 0, stream>>>(bufA, e2w1, bufB);
    k_edge<1><<<B_TOTAL / 32, 256, 0, stream>>>(bufB, e2b1, e2w2, e2b2, nbr, nullptr,
                                                wrgb, brgb, out);
}

// Round 4
// 2120.278 us; speedup vs baseline: 1.6030x; 1.5102x over previous
//
#include <hip/hip_runtime.h>
#include <hip/hip_bf16.h>
#include <math.h>

#define B_TOTAL 40960
#define NGRP 20
#define GSZ 2048
#define HPAD 68   // LDS row stride (floats) for transposed activation tiles
#define CPART 4   // candidate partitions in kNN MFMA kernel

typedef short short8 __attribute__((ext_vector_type(8)));
typedef float f32x4 __attribute__((ext_vector_type(4)));

// ---------------- group scatter ----------------
__global__ void k_scatter(const int* __restrict__ bid, int* __restrict__ grp,
                          int* __restrict__ cnt)
{
    int i = blockIdx.x * 256 + threadIdx.x;
    if (i < B_TOTAL) {
        int g = bid[i];
        int p = atomicAdd(&cnt[g], 1);
        grp[g * GSZ + p] = i;
    }
}

// ---------------- bf16 helpers (round-to-nearest-even, bit-exact, no API dep) ----------------
__device__ __forceinline__ unsigned short bf16rne(float v)
{
    unsigned int u = __float_as_uint(v);
    unsigned int r = (u + 0x7FFFu + ((u >> 16) & 1u)) >> 16;
    return (unsigned short)r;
}

// ---------------- kNN stage 1: gather -> packed bf16 hi/lo planes + norms ----------------
// xbh/xbl: [NGRP*GSZ][64] bf16 (dims 0..62, dim 63 = 0)
__global__ __launch_bounds__(256) void k_gather(const float* __restrict__ x,
    const int* __restrict__ grp, unsigned short* __restrict__ xbh,
    unsigned short* __restrict__ xbl, float* __restrict__ cn)
{
    __shared__ float tile[128][65];
    __shared__ int ids[128];
    const int tid = threadIdx.x;
    const int g = blockIdx.y;
    const int q0 = blockIdx.x * 128;
    if (tid < 128) ids[tid] = grp[g * GSZ + q0 + tid];
    __syncthreads();
    for (int s = tid; s < 128 * 64; s += 256) {
        int q = s >> 6, d = s & 63;
        tile[q][d] = (d < 63) ? x[(size_t)ids[q] * 90 + d] : 0.f;
    }
    __syncthreads();
    if (tid < 128) {
        float a = 0.f;
        #pragma unroll
        for (int d = 0; d < 63; d++) a = fmaf(tile[tid][d], tile[tid][d], a);
        cn[g * GSZ + q0 + tid] = a;
    }
    for (int s = tid; s < 128 * 32; s += 256) {
        int q = s >> 5, dp = (s & 31) << 1;
        float v0 = tile[q][dp], v1 = tile[q][dp + 1];
        unsigned short h0 = bf16rne(v0), h1 = bf16rne(v1);
        float hf0 = __uint_as_float((unsigned int)h0 << 16);
        float hf1 = __uint_as_float((unsigned int)h1 << 16);
        unsigned short l0 = bf16rne(v0 - hf0), l1 = bf16rne(v1 - hf1);
        size_t pt = (size_t)g * GSZ + q0 + q;
        ((unsigned int*)xbh)[pt * 32 + (dp >> 1)] = (unsigned int)h0 | ((unsigned int)h1 << 16);
        ((unsigned int*)xbl)[pt * 32 + (dp >> 1)] = (unsigned int)l0 | ((unsigned int)l1 << 16);
    }
}

// ---------------- top-3 insert ----------------
__device__ __forceinline__ void ins3(float d, int p,
    float& v0, float& v1, float& v2, int& p0, int& p1, int& p2)
{
    if (d < v0)      { v2 = v1; p2 = p1; v1 = v0; p1 = p0; v0 = d; p0 = p; }
    else if (d < v1) { v2 = v1; p2 = p1; v1 = d;  p1 = p; }
    else if (d < v2) { v2 = d;  p2 = p; }
}

// ---------------- kNN stage 2: MFMA distance tiles + per-part top3 ----------------
// grid: (q-tile 0..31, part 0..3, group 0..19); block = 256 = 4 indep waves of 16 queries
__global__ __launch_bounds__(256) void k_knn_mfma(const unsigned short* __restrict__ xbh,
    const unsigned short* __restrict__ xbl, const float* __restrict__ cn,
    float* __restrict__ pval, int* __restrict__ pidx)
{
    const int lane = threadIdx.x & 63;
    const int wave = threadIdx.x >> 6;
    const int g = blockIdx.z;
    const int part = blockIdx.y;
    const int qt0 = blockIdx.x * 64 + wave * 16;
    const size_t gbase = (size_t)g * GSZ;
    const int lp = lane & 15;           // point slot within fragment
    const int kg = (lane >> 4) << 3;    // k offset 0,8,16,24

    const size_t qb = (gbase + qt0 + lp) * 64;
    short8 ah0 = *(const short8*)(xbh + qb + kg);
    short8 ah1 = *(const short8*)(xbh + qb + 32 + kg);
    short8 al0 = *(const short8*)(xbl + qb + kg);
    short8 al1 = *(const short8*)(xbl + qb + 32 + kg);

    int qpos[4];
    #pragma unroll
    for (int r = 0; r < 4; r++) qpos[r] = qt0 + ((lane >> 4) << 2) + r;

    float v0_[4], v1_[4], v2_[4];
    int   p0_[4], p1_[4], p2_[4];
    #pragma unroll
    for (int r = 0; r < 4; r++) {
        v0_[r] = 1e30f; v1_[r] = 1e30f; v2_[r] = 1e30f;
        p0_[r] = 0; p1_[r] = 0; p2_[r] = 0;
    }

    const int cbeg = part * (GSZ / CPART);
    const int cend = cbeg + (GSZ / CPART);
    for (int c0 = cbeg; c0 < cend; c0 += 16) {
        const size_t cb = (gbase + c0 + lp) * 64;
        short8 bh0 = *(const short8*)(xbh + cb + kg);
        short8 bh1 = *(const short8*)(xbh + cb + 32 + kg);
        short8 bl0 = *(const short8*)(xbl + cb + kg);
        short8 bl1 = *(const short8*)(xbl + cb + 32 + kg);
        f32x4 acc = {0.f, 0.f, 0.f, 0.f};
        acc = __builtin_amdgcn_mfma_f32_16x16x32_bf16(ah0, bh0, acc, 0, 0, 0);
        acc = __builtin_amdgcn_mfma_f32_16x16x32_bf16(ah1, bh1, acc, 0, 0, 0);
        acc = __builtin_amdgcn_mfma_f32_16x16x32_bf16(al0, bh0, acc, 0, 0, 0);
        acc = __builtin_amdgcn_mfma_f32_16x16x32_bf16(al1, bh1, acc, 0, 0, 0);
        acc = __builtin_amdgcn_mfma_f32_16x16x32_bf16(ah0, bl0, acc, 0, 0, 0);
        acc = __builtin_amdgcn_mfma_f32_16x16x32_bf16(ah1, bl1, acc, 0, 0, 0);
        const float cnv = cn[gbase + c0 + lp];
        const int cpos = c0 + lp;
        #pragma unroll
        for (int r = 0; r < 4; r++) {
            float val = fmaf(-2.f, acc[r], cnv);
            if (cpos != qpos[r])
                ins3(val, cpos, v0_[r], v1_[r], v2_[r], p0_[r], p1_[r], p2_[r]);
        }
    }

    // merge across the 16 candidate-slot lanes (xor 1,2,4,8)
    #pragma unroll
    for (int r = 0; r < 4; r++) {
        #pragma unroll
        for (int m = 1; m <= 8; m <<= 1) {
            float o0 = __shfl_xor(v0_[r], m), o1 = __shfl_xor(v1_[r], m), o2 = __shfl_xor(v2_[r], m);
            int   a0 = __shfl_xor(p0_[r], m), a1 = __shfl_xor(p1_[r], m), a2 = __shfl_xor(p2_[r], m);
            ins3(o0, a0, v0_[r], v1_[r], v2_[r], p0_[r], p1_[r], p2_[r]);
            ins3(o1, a1, v0_[r], v1_[r], v2_[r], p0_[r], p1_[r], p2_[r]);
            ins3(o2, a2, v0_[r], v1_[r], v2_[r], p0_[r], p1_[r], p2_[r]);
        }
    }
    if (lp == 0) {
        #pragma unroll
        for (int r = 0; r < 4; r++) {
            size_t off = ((gbase + (size_t)qpos[r]) * CPART + part) * 3;
            pval[off + 0] = v0_[r]; pidx[off + 0] = p0_[r];
            pval[off + 1] = v1_[r]; pidx[off + 1] = p1_[r];
            pval[off + 2] = v2_[r]; pidx[off + 2] = p2_[r];
        }
    }
}

// ---------------- kNN stage 3: merge CPART partials, map to global ids ----------------
__global__ void k_knn_merge(const float* __restrict__ pval, const int* __restrict__ pidx,
                            const int* __restrict__ grp, int* __restrict__ nbr)
{
    int t = blockIdx.x * 256 + threadIdx.x;
    if (t >= NGRP * GSZ) return;
    int g = t >> 11;
    float v0 = 1e30f, v1 = 1e30f, v2 = 1e30f;
    int   p0 = 0, p1 = 0, p2 = 0;
    const float* pv = pval + (size_t)t * (CPART * 3);
    const int*   pi = pidx + (size_t)t * (CPART * 3);
    #pragma unroll
    for (int r = 0; r < CPART * 3; r++) ins3(pv[r], pi[r], v0, v1, v2, p0, p1, p2);
    int qi = grp[t];
    nbr[(size_t)qi * 3 + 0] = grp[(g << 11) + p0];
    nbr[(size_t)qi * 3 + 1] = grp[(g << 11) + p1];
    nbr[(size_t)qi * 3 + 2] = grp[(g << 11) + p2];
}

// ---------------- helpers for fp32 tile GEMMs ----------------
__device__ __forceinline__ void fma88(float acc[8][8], float4 a0, float4 a1,
                                      float4 b0, float4 b1)
{
    float av[8] = {a0.x,a0.y,a0.z,a0.w,a1.x,a1.y,a1.z,a1.w};
    float bv[8] = {b0.x,b0.y,b0.z,b0.w,b1.x,b1.y,b1.z,b1.w};
    #pragma unroll
    for (int i = 0; i < 8; i++)
        #pragma unroll
        for (int j = 0; j < 8; j++)
            acc[i][j] = fmaf(av[i], bv[j], acc[i][j]);
}

__device__ __forceinline__ void stage_w256(const float* __restrict__ W, int k0, int K,
                                           float4 st[4], int tid)
{
    #pragma unroll
    for (int u = 0; u < 4; u++) {
        int f = tid + (u << 8);
        int kk = f >> 6, c4 = (f & 63) << 2;
        int k = k0 + kk;
        st[u] = (k < K) ? *(const float4*)&W[(size_t)k * 256 + c4]
                        : make_float4(0.f, 0.f, 0.f, 0.f);
    }
}

__device__ __forceinline__ void stage_wpq(const float* __restrict__ ew1, int k0, int K,
                                          float4 st[4], int tid)
{
    #pragma unroll
    for (int u = 0; u < 4; u++) {
        int f = tid + (u << 8);
        int kk = f >> 6, c4 = (f & 63) << 2;
        int k = k0 + kk;
        if (k >= K) st[u] = make_float4(0.f, 0.f, 0.f, 0.f);
        else st[u] = (c4 < 128) ? *(const float4*)&ew1[(size_t)k * 128 + c4]
                                : *(const float4*)&ew1[(size_t)(K + k) * 128 + (c4 - 128)];
    }
}

__device__ __forceinline__ void stage_write(float (*buf)[256], const float4 st[4], int tid)
{
    #pragma unroll
    for (int u = 0; u < 4; u++) {
        int f = tid + (u << 8);
        int kk = f >> 6, c4 = (f & 63) << 2;
        *(float4*)&buf[kk][c4] = st[u];
    }
}

// ---------------- fused trunk MLP ----------------
template<int MODE>   // 0: K rows from h; 1: K rows from xyz; 2: skip (xyz then h)
__device__ __forceinline__ void trunk_layer(float (*hT)[HPAD], float (*wbuf)[16][256],
        const float* __restrict__ W, const float* __restrict__ bias,
        int K, int do_relu, float* __restrict__ gout, int row0)
{
    const int tid = threadIdx.x;
    const int tx = tid & 31, ty = tid >> 5;
    const int cLo = tx * 4, cHi = 128 + tx * 4, r0 = ty * 8;
    const int nch = (K + 15) >> 4;
    float acc[8][8];
    #pragma unroll
    for (int i = 0; i < 8; i++)
        #pragma unroll
        for (int j = 0; j < 8; j++) acc[i][j] = 0.f;

    float4 st[4];
    stage_w256(W, 0, K, st, tid);
    __syncthreads();
    stage_write(wbuf[0], st, tid);
    __syncthreads();

    for (int c = 0; c < nch; c++) {
        const int cur = c & 1;
        const bool more = (c + 1 < nch);
        if (more) stage_w256(W, (c + 1) << 4, K, st, tid);
        const float (*wb)[256] = wbuf[cur];
        const int kbase = c << 4;
        #pragma unroll
        for (int kk = 0; kk < 16; kk++) {
            const int k = kbase + kk;
            int lr;
            if (MODE == 0) lr = k;
            else if (MODE == 1) lr = 256 + k;
            else lr = (k < 63) ? (256 + k) : (k - 63);
            float4 a0 = *(const float4*)&hT[lr][r0];
            float4 a1 = *(const float4*)&hT[lr][r0 + 4];
            float4 b0 = *(const float4*)&wb[kk][cLo];
            float4 b1 = *(const float4*)&wb[kk][cHi];
            fma88(acc, a0, a1, b0, b1);
        }
        if (more) stage_write(wbuf[cur ^ 1], st, tid);
        __syncthreads();
    }

    float bL[4], bH[4];
    #pragma unroll
    for (int j = 0; j < 4; j++) { bL[j] = bias[cLo + j]; bH[j] = bias[cHi + j]; }
    #pragma unroll
    for (int i = 0; i < 8; i++)
        #pragma unroll
        for (int j = 0; j < 8; j++) {
            float v = acc[i][j] + ((j < 4) ? bL[j] : bH[j - 4]);
            acc[i][j] = do_relu ? fmaxf(v, 0.f) : v;
        }
    if (gout) {
        #pragma unroll
        for (int i = 0; i < 8; i++) {
            *(float4*)&gout[(size_t)(row0 + r0 + i) * 256 + cLo] =
                make_float4(acc[i][0], acc[i][1], acc[i][2], acc[i][3]);
            *(float4*)&gout[(size_t)(row0 + r0 + i) * 256 + cHi] =
                make_float4(acc[i][4], acc[i][5], acc[i][6], acc[i][7]);
        }
    } else {
        #pragma unroll
        for (int j = 0; j < 4; j++) {
            *(float4*)&hT[cLo + j][r0]     = make_float4(acc[0][j], acc[1][j], acc[2][j], acc[3][j]);
            *(float4*)&hT[cLo + j][r0 + 4] = make_float4(acc[4][j], acc[5][j], acc[6][j], acc[7][j]);
            *(float4*)&hT[cHi + j][r0]     = make_float4(acc[0][j+4], acc[1][j+4], acc[2][j+4], acc[3][j+4]);
            *(float4*)&hT[cHi + j][r0 + 4] = make_float4(acc[4][j+4], acc[5][j+4], acc[6][j+4], acc[7][j+4]);
        }
    }
}

__global__ __launch_bounds__(256) void k_trunk(const float* __restrict__ x,
    const float* __restrict__ w0, const float* __restrict__ b0,
    const float* __restrict__ wmid, const float* __restrict__ bmid,
    const float* __restrict__ wskip, const float* __restrict__ bskip,
    const float* __restrict__ wfin, const float* __restrict__ bfin,
    const float* __restrict__ wsig, const float* __restrict__ bsig,
    float* __restrict__ feat, float* __restrict__ out)
{
    __shared__ float hT[320][HPAD];
    __shared__ float wbuf[2][16][256];
    const int tid = threadIdx.x;
    const int row0 = blockIdx.x * 64;
    for (int s = tid; s < 64 * 64; s += 256) {
        int k = s >> 6, r = s & 63;
        hT[256 + k][r] = (k < 63) ? x[(size_t)(row0 + r) * 90 + k] : 0.f;
    }
    trunk_layer<1>(hT, wbuf, w0, b0, 63, 1, nullptr, row0);
    trunk_layer<0>(hT, wbuf, wmid + 0*65536, bmid + 0*256, 256, 1, nullptr, row0);
    trunk_layer<0>(hT, wbuf, wmid + 1*65536, bmid + 1*256, 256, 1, nullptr, row0);
    trunk_layer<0>(hT, wbuf, wmid + 2*65536, bmid + 2*256, 256, 1, nullptr, row0);
    trunk_layer<2>(hT, wbuf, wskip, bskip, 319, 1, nullptr, row0);
    trunk_layer<0>(hT, wbuf, wmid + 3*65536, bmid + 3*256, 256, 1, nullptr, row0);
    trunk_layer<0>(hT, wbuf, wmid + 4*65536, bmid + 4*256, 256, 1, nullptr, row0);
    trunk_layer<0>(hT, wbuf, wmid + 5*65536, bmid + 5*256, 256, 1, nullptr, row0);
    trunk_layer<0>(hT, wbuf, wfin, bfin, 256, 0, feat, row0);   // feat, no relu
    __syncthreads();
    if (tid < 64) {
        float s = bsig[0];
        for (int k = 0; k < 256; k++) s = fmaf(hT[k][tid], wsig[k], s);
        out[(size_t)(row0 + tid) * 4 + 3] = s;
    }
}

// ---------------- PQ GEMMs for edge convs ----------------
__global__ __launch_bounds__(256) void k_pq1(const float* __restrict__ feat,
    const float* __restrict__ x, const float* __restrict__ ew1,
    float* __restrict__ PQ)
{
    __shared__ float aT[288][HPAD];
    __shared__ float wbuf[2][16][256];
    const int tid = threadIdx.x;
    const int tx = tid & 31, ty = tid >> 5;
    const int cLo = tx * 4, cHi = 128 + tx * 4, r0 = ty * 8;
    const int row0 = blockIdx.x * 64;
    const int K = 283;
    for (int s = tid; s < 64 * 256; s += 256) {
        int r = s >> 8, k = s & 255;
        aT[k][r] = feat[(size_t)(row0 + r) * 256 + k];
    }
    for (int s = tid; s < 32 * 64; s += 256) {
        int dd = s >> 6, r = s & 63;
        aT[256 + dd][r] = (dd < 27) ? x[(size_t)(row0 + r) * 90 + 63 + dd] : 0.f;
    }
    float4 st[4];
    stage_wpq(ew1, 0, K, st, tid);
    __syncthreads();
    stage_write(wbuf[0], st, tid);
    __syncthreads();

    float acc[8][8];
    #pragma unroll
    for (int i = 0; i < 8; i++)
        #pragma unroll
        for (int j = 0; j < 8; j++) acc[i][j] = 0.f;

    const int nch = (K + 15) >> 4;
    for (int c = 0; c < nch; c++) {
        const int cur = c & 1;
        const bool more = (c + 1 < nch);
        if (more) stage_wpq(ew1, (c + 1) << 4, K, st, tid);
        const float (*wb)[256] = wbuf[cur];
        const int kbase = c << 4;
        #pragma unroll
        for (int kk = 0; kk < 16; kk++) {
            const int k = kbase + kk;
            float4 a0 = *(const float4*)&aT[k][r0];
            float4 a1 = *(const float4*)&aT[k][r0 + 4];
            float4 b0 = *(const float4*)&wb[kk][cLo];
            float4 b1 = *(const float4*)&wb[kk][cHi];
            fma88(acc, a0, a1, b0, b1);
        }
        if (more) stage_write(wbuf[cur ^ 1], st, tid);
        __syncthreads();
    }
    #pragma unroll
    for (int i = 0; i < 8; i++) {
        *(float4*)&PQ[(size_t)(row0 + r0 + i) * 256 + cLo] =
            make_float4(acc[i][0], acc[i][1], acc[i][2], acc[i][3]);
        *(float4*)&PQ[(size_t)(row0 + r0 + i) * 256 + cHi] =
            make_float4(acc[i][4], acc[i][5], acc[i][6], acc[i][7]);
    }
}

__global__ __launch_bounds__(256) void k_pq2(const float* __restrict__ d1,
    const float* __restrict__ ew1, float* __restrict__ PQ)
{
    __shared__ float aT[128][HPAD];
    __shared__ float wbuf[2][16][256];
    const int tid = threadIdx.x;
    const int tx = tid & 31, ty = tid >> 5;
    const int cLo = tx * 4, cHi = 128 + tx * 4, r0 = ty * 8;
    const int row0 = blockIdx.x * 64;
    const int K = 128;
    for (int s = tid; s < 64 * 128; s += 256) {
        int r = s >> 7, k = s & 127;
        aT[k][r] = d1[(size_t)(row0 + r) * 128 + k];
    }
    float4 st[4];
    stage_wpq(ew1, 0, K, st, tid);
    __syncthreads();
    stage_write(wbuf[0], st, tid);
    __syncthreads();

    float acc[8][8];
    #pragma unroll
    for (int i = 0; i < 8; i++)
        #pragma unroll
        for (int j = 0; j < 8; j++) acc[i][j] = 0.f;

    for (int c = 0; c < 8; c++) {
        const int cur = c & 1;
        const bool more = (c < 7);
        if (more) stage_wpq(ew1, (c + 1) << 4, K, st, tid);
        const float (*wb)[256] = wbuf[cur];
        const int kbase = c << 4;
        #pragma unroll
        for (int kk = 0; kk < 16; kk++) {
            const int k = kbase + kk;
            float4 a0 = *(const float4*)&aT[k][r0];
            float4 a1 = *(const float4*)&aT[k][r0 + 4];
            float4 b0 = *(const float4*)&wb[kk][cLo];
            float4 b1 = *(const float4*)&wb[kk][cHi];
            fma88(acc, a0, a1, b0, b1);
        }
        if (more) stage_write(wbuf[cur ^ 1], st, tid);
        __syncthreads();
    }
    #pragma unroll
    for (int i = 0; i < 8; i++) {
        *(float4*)&PQ[(size_t)(row0 + r0 + i) * 256 + cLo] =
            make_float4(acc[i][0], acc[i][1], acc[i][2], acc[i][3]);
        *(float4*)&PQ[(size_t)(row0 + r0 + i) * 256 + cHi] =
            make_float4(acc[i][4], acc[i][5], acc[i][6], acc[i][7]);
    }
}

// ---------------- edge conv ----------------
template<int RGB>
__global__ __launch_bounds__(256) void k_edge(const float* __restrict__ PQ,
    const float* __restrict__ b1, const float* __restrict__ w2,
    const float* __restrict__ b2, const int* __restrict__ nbr,
    float* __restrict__ dout,
    const float* __restrict__ wrgb, const float* __restrict__ brgb,
    float* __restrict__ out)
{
    __shared__ float h1T[128][97];
    __shared__ float wb[32][128];
    const int tid = threadIdx.x;
    const int n0 = blockIdx.x * 32;
    {
        const int c = tid & 127, eg = tid >> 7;
        const float bias = b1[c];
        for (int e = eg; e < 96; e += 2) {
            int n = e / 3;
            int jj = e - n * 3;
            int i = n0 + n;
            int j = nbr[(size_t)i * 3 + jj];
            float v = PQ[(size_t)i * 256 + c] + bias
                    + PQ[(size_t)j * 256 + 128 + c] - PQ[(size_t)i * 256 + 128 + c];
            h1T[c][e] = fmaxf(v, 0.f);
        }
    }
    const int cg = tid & 15, rg = tid >> 4;
    const int cLo = cg * 4, cHi = 64 + cg * 4, e0 = rg * 6;
    float acc[6][8];
    #pragma unroll
    for (int m = 0; m < 6; m++)
        #pragma unroll
        for (int j = 0; j < 8; j++) acc[m][j] = 0.f;
    for (int k0 = 0; k0 < 128; k0 += 32) {
        __syncthreads();
        for (int s = tid; s < 32 * 128; s += 256) {
            int kk = s >> 7, c = s & 127;
            wb[kk][c] = w2[(size_t)(k0 + kk) * 128 + c];
        }
        __syncthreads();
        for (int kk = 0; kk < 32; kk++) {
            const int k = k0 + kk;
            float av[6];
            #pragma unroll
            for (int m = 0; m < 6; m++) av[m] = h1T[k][e0 + m];
            float4 w0v = *(const float4*)&wb[kk][cLo];
            float4 w1v = *(const float4*)&wb[kk][cHi];
            float bv[8] = {w0v.x,w0v.y,w0v.z,w0v.w,w1v.x,w1v.y,w1v.z,w1v.w};
            #pragma unroll
            for (int m = 0; m < 6; m++)
                #pragma unroll
                for (int j = 0; j < 8; j++)
                    acc[m][j] = fmaf(av[m], bv[j], acc[m][j]);
        }
    }
    float bb[8];
    #pragma unroll
    for (int j = 0; j < 8; j++) bb[j] = b2[(j < 4) ? (cLo + j) : (cHi + j - 4)];
    float dA[8], dB[8];
    #pragma unroll
    for (int j = 0; j < 8; j++) {
        float h0 = fmaxf(acc[0][j] + bb[j], 0.f);
        float h1 = fmaxf(acc[1][j] + bb[j], 0.f);
        float h2 = fmaxf(acc[2][j] + bb[j], 0.f);
        float h3 = fmaxf(acc[3][j] + bb[j], 0.f);
        float h4 = fmaxf(acc[4][j] + bb[j], 0.f);
        float h5 = fmaxf(acc[5][j] + bb[j], 0.f);
        dA[j] = (h0 + h1 + h2) * (1.f / 3.f);
        dB[j] = (h3 + h4 + h5) * (1.f / 3.f);
    }
    if (!RGB) {
        *(float4*)&dout[(size_t)(n0 + 2*rg) * 128 + cLo] = make_float4(dA[0], dA[1], dA[2], dA[3]);
        *(float4*)&dout[(size_t)(n0 + 2*rg) * 128 + cHi] = make_float4(dA[4], dA[5], dA[6], dA[7]);
        *(float4*)&dout[(size_t)(n0 + 2*rg + 1) * 128 + cLo] = make_float4(dB[0], dB[1], dB[2], dB[3]);
        *(float4*)&dout[(size_t)(n0 + 2*rg + 1) * 128 + cHi] = make_float4(dB[4], dB[5], dB[6], dB[7]);
    } else {
        __syncthreads();
        float* d2L = &h1T[0][0];
        #pragma unroll
        for (int j = 0; j < 4; j++) {
            d2L[(2*rg)     * 130 + cLo + j] = dA[j];
            d2L[(2*rg)     * 130 + cHi + j] = dA[j + 4];
            d2L[(2*rg + 1) * 130 + cLo + j] = dB[j];
            d2L[(2*rg + 1) * 130 + cHi + j] = dB[j + 4];
        }
        __syncthreads();
        if (tid < 96) {
            int n = tid / 3, ch = tid - 3 * (tid / 3);
            float s = brgb[ch];
            for (int k = 0; k < 128; k++) s = fmaf(d2L[n * 130 + k], wrgb[k * 3 + ch], s);
            out[(size_t)(n0 + n) * 4 + ch] = 1.f / (1.f + expf(-s));
        }
    }
}

// ---------------- launch ----------------
extern "C" void kernel_launch(void* const* d_in, const int* in_sizes, int n_in,
                              void* d_out, int out_size, void* d_ws, size_t ws_size,
                              hipStream_t stream)
{
    const float* x     = (const float*)d_in[0];
    const int*   bid   = (const int*)d_in[1];
    const float* w0    = (const float*)d_in[2];
    const float* b0    = (const float*)d_in[3];
    const float* wmid  = (const float*)d_in[4];
    const float* bmid  = (const float*)d_in[5];
    const float* wskip = (const float*)d_in[6];
    const float* bskip = (const float*)d_in[7];
    const float* wfin  = (const float*)d_in[8];
    const float* bfin  = (const float*)d_in[9];
    const float* wsig  = (const float*)d_in[10];
    const float* bsig  = (const float*)d_in[11];
    const float* e1w1  = (const float*)d_in[12];
    const float* e1b1  = (const float*)d_in[13];
    const float* e1w2  = (const float*)d_in[14];
    const float* e1b2  = (const float*)d_in[15];
    const float* e2w1  = (const float*)d_in[16];
    const float* e2b1  = (const float*)d_in[17];
    const float* e2w2  = (const float*)d_in[18];
    const float* e2b2  = (const float*)d_in[19];
    const float* wrgb  = (const float*)d_in[20];
    const float* brgb  = (const float*)d_in[21];
    float* out = (float*)d_out;

    char* ws = (char*)d_ws;
    int* cnt = (int*)ws;                                   // 20 ints
    int* grp = (int*)(ws + 256);                           // 20*2048 ints
    int* nbr = (int*)(ws + 256 + NGRP * GSZ * 4);          // 40960*3 ints
    float* bufA = (float*)(ws + (1 << 20));                // 40960*256 f32 (feat, later d1)
    float* bufB = bufA + (size_t)B_TOTAL * 256;            // 40960*256 f32 (PQ1, later PQ2)

    // kNN scratch overlays bufA/bufB (dead before trunk/pq writes):
    unsigned short* xbh = (unsigned short*)bufA;                       // 40960*64 bf16 = 5.24 MB
    unsigned short* xbl = xbh + (size_t)B_TOTAL * 64;                  // 5.24 MB
    float* cn   = (float*)(xbl + (size_t)B_TOTAL * 64);                // 160 KB
    float* pval = cn + B_TOTAL;                                        // 40960*12 f32
    int*   pidx = (int*)(pval + (size_t)B_TOTAL * CPART * 3);          // 40960*12 int

    hipMemsetAsync(cnt, 0, 256, stream);
    k_scatter<<<B_TOTAL / 256, 256, 0, stream>>>(bid, grp, cnt);
    k_gather<<<dim3(GSZ / 128, NGRP), 256, 0, stream>>>(x, grp, xbh, xbl, cn);
    k_knn_mfma<<<dim3(GSZ / 64, CPART, NGRP), 256, 0, stream>>>(xbh, xbl, cn, pval, pidx);
    k_knn_merge<<<(NGRP * GSZ + 255) / 256, 256, 0, stream>>>(pval, pidx, grp, nbr);
    k_trunk<<<B_TOTAL / 64, 256, 0, stream>>>(x, w0, b0, wmid, bmid, wskip, bskip,
                                              wfin, bfin, wsig, bsig, bufA, out);
    k_pq1<<<B_TOTAL / 64, 256, 0, stream>>>(bufA, x, e1w1, bufB);
    k_edge<0><<<B_TOTAL / 32, 256, 0, stream>>>(bufB, e1b1, e1w2, e1b2, nbr, bufA,
                                                nullptr, nullptr, nullptr);
    k_pq2<<<B_TOTAL / 64, 256, 0, stream>>>(bufA, e2w1, bufB);
    k_edge<1><<<B_TOTAL / 32, 256, 0, stream>>>(bufB, e2b1, e2w2, e2b2, nbr, nullptr,
                                                wrgb, brgb, out);
}

// Round 5
// 1785.246 us; speedup vs baseline: 1.9038x; 1.1877x over previous
//
#include <hip/hip_runtime.h>
#include <hip/hip_bf16.h>
#include <math.h>

#define B_TOTAL 40960
#define NGRP 20
#define GSZ 2048
#define HPAD 68
#define CPART 4

typedef short short8 __attribute__((ext_vector_type(8)));
typedef float f32x4 __attribute__((ext_vector_type(4)));
typedef float f32x16 __attribute__((ext_vector_type(16)));

// ---------------- group scatter ----------------
__global__ void k_scatter(const int* __restrict__ bid, int* __restrict__ grp,
                          int* __restrict__ cnt)
{
    int i = blockIdx.x * 256 + threadIdx.x;
    if (i < B_TOTAL) {
        int g = bid[i];
        int p = atomicAdd(&cnt[g], 1);
        grp[g * GSZ + p] = i;
    }
}

// ---------------- bf16 helpers ----------------
__device__ __forceinline__ unsigned short bf16rne(float v)
{
    unsigned int u = __float_as_uint(v);
    unsigned int r = (u + 0x7FFFu + ((u >> 16) & 1u)) >> 16;
    return (unsigned short)r;
}

__device__ __forceinline__ void splitbf16(const float* v, short8& hi, short8& lo)
{
    #pragma unroll
    for (int j = 0; j < 8; j++) {
        unsigned short h = bf16rne(v[j]);
        hi[j] = (short)h;
        float hf = __uint_as_float((unsigned int)h << 16);
        lo[j] = (short)bf16rne(v[j] - hf);
    }
}

// ---------------- kNN stage 1: gather -> packed bf16 hi/lo planes + norms ----------------
__global__ __launch_bounds__(256) void k_gather(const float* __restrict__ x,
    const int* __restrict__ grp, unsigned short* __restrict__ xbh,
    unsigned short* __restrict__ xbl, float* __restrict__ cn)
{
    __shared__ float tile[128][65];
    __shared__ int ids[128];
    const int tid = threadIdx.x;
    const int g = blockIdx.y;
    const int q0 = blockIdx.x * 128;
    if (tid < 128) ids[tid] = grp[g * GSZ + q0 + tid];
    __syncthreads();
    for (int s = tid; s < 128 * 64; s += 256) {
        int q = s >> 6, d = s & 63;
        tile[q][d] = (d < 63) ? x[(size_t)ids[q] * 90 + d] : 0.f;
    }
    __syncthreads();
    if (tid < 128) {
        float a = 0.f;
        #pragma unroll
        for (int d = 0; d < 63; d++) a = fmaf(tile[tid][d], tile[tid][d], a);
        cn[g * GSZ + q0 + tid] = a;
    }
    for (int s = tid; s < 128 * 32; s += 256) {
        int q = s >> 5, dp = (s & 31) << 1;
        float v0 = tile[q][dp], v1 = tile[q][dp + 1];
        unsigned short h0 = bf16rne(v0), h1 = bf16rne(v1);
        float hf0 = __uint_as_float((unsigned int)h0 << 16);
        float hf1 = __uint_as_float((unsigned int)h1 << 16);
        unsigned short l0 = bf16rne(v0 - hf0), l1 = bf16rne(v1 - hf1);
        size_t pt = (size_t)g * GSZ + q0 + q;
        ((unsigned int*)xbh)[pt * 32 + (dp >> 1)] = (unsigned int)h0 | ((unsigned int)h1 << 16);
        ((unsigned int*)xbl)[pt * 32 + (dp >> 1)] = (unsigned int)l0 | ((unsigned int)l1 << 16);
    }
}

// ---------------- top-3 insert ----------------
__device__ __forceinline__ void ins3(float d, int p,
    float& v0, float& v1, float& v2, int& p0, int& p1, int& p2)
{
    if (d < v0)      { v2 = v1; p2 = p1; v1 = v0; p1 = p0; v0 = d; p0 = p; }
    else if (d < v1) { v2 = v1; p2 = p1; v1 = d;  p1 = p; }
    else if (d < v2) { v2 = d;  p2 = p; }
}

// ---------------- kNN stage 2: MFMA distance tiles + per-part top3 ----------------
__global__ __launch_bounds__(256) void k_knn_mfma(const unsigned short* __restrict__ xbh,
    const unsigned short* __restrict__ xbl, const float* __restrict__ cn,
    float* __restrict__ pval, int* __restrict__ pidx)
{
    const int lane = threadIdx.x & 63;
    const int wave = threadIdx.x >> 6;
    const int g = blockIdx.z;
    const int part = blockIdx.y;
    const int qt0 = blockIdx.x * 64 + wave * 16;
    const size_t gbase = (size_t)g * GSZ;
    const int lp = lane & 15;
    const int kg = (lane >> 4) << 3;

    const size_t qb = (gbase + qt0 + lp) * 64;
    short8 ah0 = *(const short8*)(xbh + qb + kg);
    short8 ah1 = *(const short8*)(xbh + qb + 32 + kg);
    short8 al0 = *(const short8*)(xbl + qb + kg);
    short8 al1 = *(const short8*)(xbl + qb + 32 + kg);

    int qpos[4];
    #pragma unroll
    for (int r = 0; r < 4; r++) qpos[r] = qt0 + ((lane >> 4) << 2) + r;

    float v0_[4], v1_[4], v2_[4];
    int   p0_[4], p1_[4], p2_[4];
    #pragma unroll
    for (int r = 0; r < 4; r++) {
        v0_[r] = 1e30f; v1_[r] = 1e30f; v2_[r] = 1e30f;
        p0_[r] = 0; p1_[r] = 0; p2_[r] = 0;
    }

    const int cbeg = part * (GSZ / CPART);
    const int cend = cbeg + (GSZ / CPART);
    for (int c0 = cbeg; c0 < cend; c0 += 16) {
        const size_t cb = (gbase + c0 + lp) * 64;
        short8 bh0 = *(const short8*)(xbh + cb + kg);
        short8 bh1 = *(const short8*)(xbh + cb + 32 + kg);
        short8 bl0 = *(const short8*)(xbl + cb + kg);
        short8 bl1 = *(const short8*)(xbl + cb + 32 + kg);
        f32x4 acc = {0.f, 0.f, 0.f, 0.f};
        acc = __builtin_amdgcn_mfma_f32_16x16x32_bf16(ah0, bh0, acc, 0, 0, 0);
        acc = __builtin_amdgcn_mfma_f32_16x16x32_bf16(ah1, bh1, acc, 0, 0, 0);
        acc = __builtin_amdgcn_mfma_f32_16x16x32_bf16(al0, bh0, acc, 0, 0, 0);
        acc = __builtin_amdgcn_mfma_f32_16x16x32_bf16(al1, bh1, acc, 0, 0, 0);
        acc = __builtin_amdgcn_mfma_f32_16x16x32_bf16(ah0, bl0, acc, 0, 0, 0);
        acc = __builtin_amdgcn_mfma_f32_16x16x32_bf16(ah1, bl1, acc, 0, 0, 0);
        const float cnv = cn[gbase + c0 + lp];
        const int cpos = c0 + lp;
        #pragma unroll
        for (int r = 0; r < 4; r++) {
            float val = fmaf(-2.f, acc[r], cnv);
            if (cpos != qpos[r])
                ins3(val, cpos, v0_[r], v1_[r], v2_[r], p0_[r], p1_[r], p2_[r]);
        }
    }

    #pragma unroll
    for (int r = 0; r < 4; r++) {
        #pragma unroll
        for (int m = 1; m <= 8; m <<= 1) {
            float o0 = __shfl_xor(v0_[r], m), o1 = __shfl_xor(v1_[r], m), o2 = __shfl_xor(v2_[r], m);
            int   a0 = __shfl_xor(p0_[r], m), a1 = __shfl_xor(p1_[r], m), a2 = __shfl_xor(p2_[r], m);
            ins3(o0, a0, v0_[r], v1_[r], v2_[r], p0_[r], p1_[r], p2_[r]);
            ins3(o1, a1, v0_[r], v1_[r], v2_[r], p0_[r], p1_[r], p2_[r]);
            ins3(o2, a2, v0_[r], v1_[r], v2_[r], p0_[r], p1_[r], p2_[r]);
        }
    }
    if (lp == 0) {
        #pragma unroll
        for (int r = 0; r < 4; r++) {
            size_t off = ((gbase + (size_t)qpos[r]) * CPART + part) * 3;
            pval[off + 0] = v0_[r]; pidx[off + 0] = p0_[r];
            pval[off + 1] = v1_[r]; pidx[off + 1] = p1_[r];
            pval[off + 2] = v2_[r]; pidx[off + 2] = p2_[r];
        }
    }
}

// ---------------- kNN stage 3 ----------------
__global__ void k_knn_merge(const float* __restrict__ pval, const int* __restrict__ pidx,
                            const int* __restrict__ grp, int* __restrict__ nbr)
{
    int t = blockIdx.x * 256 + threadIdx.x;
    if (t >= NGRP * GSZ) return;
    int g = t >> 11;
    float v0 = 1e30f, v1 = 1e30f, v2 = 1e30f;
    int   p0 = 0, p1 = 0, p2 = 0;
    const float* pv = pval + (size_t)t * (CPART * 3);
    const int*   pi = pidx + (size_t)t * (CPART * 3);
    #pragma unroll
    for (int r = 0; r < CPART * 3; r++) ins3(pv[r], pi[r], v0, v1, v2, p0, p1, p2);
    int qi = grp[t];
    nbr[(size_t)qi * 3 + 0] = grp[(g << 11) + p0];
    nbr[(size_t)qi * 3 + 1] = grp[(g << 11) + p1];
    nbr[(size_t)qi * 3 + 2] = grp[(g << 11) + p2];
}

// ---------------- trunk weight prep: split-bf16, fragment-major ----------------
// layers: 0:w0(Kp64) 1-3:wmid0-2 4:skip(Kp320, K-order=[h,xyz]) 5-7:wmid3-5 8:wfin
// frag layout: [(ct*KC+kc)*2+plane][lane(64)][8] bf16, layer base = CUM[L]*8192 elems
__global__ void k_wprep(const float* __restrict__ w0, const float* __restrict__ wmid,
                        const float* __restrict__ wskip, const float* __restrict__ wfin,
                        unsigned short* __restrict__ wfrag)
{
    int t = blockIdx.x * 256 + threadIdx.x;
    if (t >= 557056) return;
    const int CUMa[10] = {0,4,20,36,52,72,88,104,120,136};
    const int KCa[9]   = {4,16,16,16,20,16,16,16,16};
    int q = t >> 12;
    int L = 0;
    #pragma unroll
    for (int i = 0; i < 9; i++) if (q >= CUMa[i + 1]) L = i + 1;
    int cum = 0, kcn = 16;
    #pragma unroll
    for (int i = 0; i < 9; i++) if (L == i) { cum = CUMa[i]; kcn = KCa[i]; }
    int u = t - (cum << 12);
    int j = u & 7, lane = (u >> 3) & 63;
    int ckk = u >> 9;
    int kc = ckk % kcn, ct = ckk / kcn;
    int col = ct * 32 + (lane & 31);
    int k = kc * 16 + ((lane >> 5) << 3) + j;
    float w;
    if (L == 0)      w = (k < 63)  ? w0[k * 256 + col] : 0.f;
    else if (L == 4) w = (k < 256) ? wskip[(63 + k) * 256 + col]
                       : (k < 319) ? wskip[(k - 256) * 256 + col] : 0.f;
    else if (L == 8) w = wfin[k * 256 + col];
    else {
        int m = (L <= 3) ? (L - 1) : (L - 2);
        w = wmid[(size_t)m * 65536 + k * 256 + col];
    }
    unsigned short hi = bf16rne(w);
    float hf = __uint_as_float((unsigned int)hi << 16);
    unsigned short lo = bf16rne(w - hf);
    size_t base = ((size_t)cum << 13) + (size_t)(ct * kcn + kc) * 1024 + lane * 8 + j;
    wfrag[base] = hi;
    wfrag[base + 512] = lo;
}

// ---------------- fused trunk MLP via split-bf16 MFMA (1 wave / 32 rows, no barriers) ----------------
template<int KCH, int KCX, int OUTMODE>   // OUTMODE 0: relu->LDS H; 1: no relu -> global feat
__device__ __forceinline__ void mlayer(float (*H)[260], int rowbase,
    const float* __restrict__ x, const unsigned short* __restrict__ wl,
    const float* __restrict__ bias, float* __restrict__ gout, int lane)
{
    const int r31 = lane & 31, g = lane >> 5;
    constexpr int KC = KCH + KCX;
    short8 Ah[KC], Al[KC];
    #pragma unroll
    for (int kc = 0; kc < KCH; kc++) {
        float v[8];
        float4 a = *(const float4*)&H[r31][kc * 16 + g * 8];
        float4 b = *(const float4*)&H[r31][kc * 16 + g * 8 + 4];
        v[0]=a.x; v[1]=a.y; v[2]=a.z; v[3]=a.w; v[4]=b.x; v[5]=b.y; v[6]=b.z; v[7]=b.w;
        splitbf16(v, Ah[kc], Al[kc]);
    }
    #pragma unroll
    for (int t = 0; t < KCX; t++) {
        float v[8];
        #pragma unroll
        for (int j = 0; j < 8; j++) {
            int kx = t * 16 + g * 8 + j;
            v[j] = (kx < 63) ? x[(size_t)(rowbase + r31) * 90 + kx] : 0.f;
        }
        splitbf16(v, Ah[KCH + t], Al[KCH + t]);
    }
    for (int ct = 0; ct < 8; ct++) {
        f32x16 acc;
        #pragma unroll
        for (int r = 0; r < 16; r++) acc[r] = 0.f;
        const unsigned short* wp = wl + (size_t)ct * KC * 1024 + lane * 8;
        #pragma unroll
        for (int kc = 0; kc < KC; kc++) {
            short8 bh = *(const short8*)(wp + kc * 1024);
            short8 bl = *(const short8*)(wp + kc * 1024 + 512);
            acc = __builtin_amdgcn_mfma_f32_32x32x16_bf16(Ah[kc], bh, acc, 0, 0, 0);
            acc = __builtin_amdgcn_mfma_f32_32x32x16_bf16(Al[kc], bh, acc, 0, 0, 0);
            acc = __builtin_amdgcn_mfma_f32_32x32x16_bf16(Ah[kc], bl, acc, 0, 0, 0);
        }
        float bv = bias[ct * 32 + r31];
        #pragma unroll
        for (int r = 0; r < 16; r++) {
            int row = (r & 3) + 8 * (r >> 2) + 4 * g;
            float vv = acc[r] + bv;
            if (OUTMODE == 0) {
                H[row][ct * 32 + r31] = fmaxf(vv, 0.f);
            } else {
                gout[(size_t)(rowbase + row) * 256 + ct * 32 + r31] = vv;
            }
        }
    }
}

__global__ __launch_bounds__(64) void k_trunk_mfma(const float* __restrict__ x,
    const unsigned short* __restrict__ wfrag,
    const float* __restrict__ b0, const float* __restrict__ bmid,
    const float* __restrict__ bskip, const float* __restrict__ bfin,
    const float* __restrict__ wsig, const float* __restrict__ bsig,
    float* __restrict__ feat, float* __restrict__ out)
{
    __shared__ float H[32][260];
    const int lane = threadIdx.x;
    const int rowbase = blockIdx.x * 32;
    const unsigned short* W = wfrag;
    mlayer<0, 4, 0>(H, rowbase, x, W + (size_t)0   * 8192, b0,          nullptr, lane);
    mlayer<16,0, 0>(H, rowbase, x, W + (size_t)4   * 8192, bmid + 0,    nullptr, lane);
    mlayer<16,0, 0>(H, rowbase, x, W + (size_t)20  * 8192, bmid + 256,  nullptr, lane);
    mlayer<16,0, 0>(H, rowbase, x, W + (size_t)36  * 8192, bmid + 512,  nullptr, lane);
    mlayer<16,4, 0>(H, rowbase, x, W + (size_t)52  * 8192, bskip,       nullptr, lane);
    mlayer<16,0, 0>(H, rowbase, x, W + (size_t)72  * 8192, bmid + 768,  nullptr, lane);
    mlayer<16,0, 0>(H, rowbase, x, W + (size_t)88  * 8192, bmid + 1024, nullptr, lane);
    mlayer<16,0, 0>(H, rowbase, x, W + (size_t)104 * 8192, bmid + 1280, nullptr, lane);
    mlayer<16,0, 1>(H, rowbase, x, W + (size_t)120 * 8192, bfin,        feat,    lane);
    // sigma from final h (rows wave-private, no barrier needed)
    const int r31 = lane & 31, g = lane >> 5;
    float s = 0.f;
    #pragma unroll
    for (int kk = 0; kk < 32; kk++) {
        float4 hv = *(const float4*)&H[r31][g * 128 + kk * 4];
        float4 wv = *(const float4*)&wsig[g * 128 + kk * 4];
        s += hv.x * wv.x + hv.y * wv.y + hv.z * wv.z + hv.w * wv.w;
    }
    s += __shfl_xor(s, 32);
    if (lane < 32) out[(size_t)(rowbase + r31) * 4 + 3] = s + bsig[0];
}

// ---------------- helpers for fp32 tile GEMMs (pq/edge, unchanged) ----------------
__device__ __forceinline__ void fma88(float acc[8][8], float4 a0, float4 a1,
                                      float4 b0, float4 b1)
{
    float av[8] = {a0.x,a0.y,a0.z,a0.w,a1.x,a1.y,a1.z,a1.w};
    float bv[8] = {b0.x,b0.y,b0.z,b0.w,b1.x,b1.y,b1.z,b1.w};
    #pragma unroll
    for (int i = 0; i < 8; i++)
        #pragma unroll
        for (int j = 0; j < 8; j++)
            acc[i][j] = fmaf(av[i], bv[j], acc[i][j]);
}

__device__ __forceinline__ void stage_wpq(const float* __restrict__ ew1, int k0, int K,
                                          float4 st[4], int tid)
{
    #pragma unroll
    for (int u = 0; u < 4; u++) {
        int f = tid + (u << 8);
        int kk = f >> 6, c4 = (f & 63) << 2;
        int k = k0 + kk;
        if (k >= K) st[u] = make_float4(0.f, 0.f, 0.f, 0.f);
        else st[u] = (c4 < 128) ? *(const float4*)&ew1[(size_t)k * 128 + c4]
                                : *(const float4*)&ew1[(size_t)(K + k) * 128 + (c4 - 128)];
    }
}

__device__ __forceinline__ void stage_write(float (*buf)[256], const float4 st[4], int tid)
{
    #pragma unroll
    for (int u = 0; u < 4; u++) {
        int f = tid + (u << 8);
        int kk = f >> 6, c4 = (f & 63) << 2;
        *(float4*)&buf[kk][c4] = st[u];
    }
}

// ---------------- PQ GEMMs for edge convs ----------------
__global__ __launch_bounds__(256) void k_pq1(const float* __restrict__ feat,
    const float* __restrict__ x, const float* __restrict__ ew1,
    float* __restrict__ PQ)
{
    __shared__ float aT[288][HPAD];
    __shared__ float wbuf[2][16][256];
    const int tid = threadIdx.x;
    const int tx = tid & 31, ty = tid >> 5;
    const int cLo = tx * 4, cHi = 128 + tx * 4, r0 = ty * 8;
    const int row0 = blockIdx.x * 64;
    const int K = 283;
    for (int s = tid; s < 64 * 256; s += 256) {
        int r = s >> 8, k = s & 255;
        aT[k][r] = feat[(size_t)(row0 + r) * 256 + k];
    }
    for (int s = tid; s < 32 * 64; s += 256) {
        int dd = s >> 6, r = s & 63;
        aT[256 + dd][r] = (dd < 27) ? x[(size_t)(row0 + r) * 90 + 63 + dd] : 0.f;
    }
    float4 st[4];
    stage_wpq(ew1, 0, K, st, tid);
    __syncthreads();
    stage_write(wbuf[0], st, tid);
    __syncthreads();

    float acc[8][8];
    #pragma unroll
    for (int i = 0; i < 8; i++)
        #pragma unroll
        for (int j = 0; j < 8; j++) acc[i][j] = 0.f;

    const int nch = (K + 15) >> 4;
    for (int c = 0; c < nch; c++) {
        const int cur = c & 1;
        const bool more = (c + 1 < nch);
        if (more) stage_wpq(ew1, (c + 1) << 4, K, st, tid);
        const float (*wb)[256] = wbuf[cur];
        const int kbase = c << 4;
        #pragma unroll
        for (int kk = 0; kk < 16; kk++) {
            const int k = kbase + kk;
            float4 a0 = *(const float4*)&aT[k][r0];
            float4 a1 = *(const float4*)&aT[k][r0 + 4];
            float4 b0 = *(const float4*)&wb[kk][cLo];
            float4 b1 = *(const float4*)&wb[kk][cHi];
            fma88(acc, a0, a1, b0, b1);
        }
        if (more) stage_write(wbuf[cur ^ 1], st, tid);
        __syncthreads();
    }
    #pragma unroll
    for (int i = 0; i < 8; i++) {
        *(float4*)&PQ[(size_t)(row0 + r0 + i) * 256 + cLo] =
            make_float4(acc[i][0], acc[i][1], acc[i][2], acc[i][3]);
        *(float4*)&PQ[(size_t)(row0 + r0 + i) * 256 + cHi] =
            make_float4(acc[i][4], acc[i][5], acc[i][6], acc[i][7]);
    }
}

__global__ __launch_bounds__(256) void k_pq2(const float* __restrict__ d1,
    const float* __restrict__ ew1, float* __restrict__ PQ)
{
    __shared__ float aT[128][HPAD];
    __shared__ float wbuf[2][16][256];
    const int tid = threadIdx.x;
    const int tx = tid & 31, ty = tid >> 5;
    const int cLo = tx * 4, cHi = 128 + tx * 4, r0 = ty * 8;
    const int row0 = blockIdx.x * 64;
    const int K = 128;
    for (int s = tid; s < 64 * 128; s += 256) {
        int r = s >> 7, k = s & 127;
        aT[k][r] = d1[(size_t)(row0 + r) * 128 + k];
    }
    float4 st[4];
    stage_wpq(ew1, 0, K, st, tid);
    __syncthreads();
    stage_write(wbuf[0], st, tid);
    __syncthreads();

    float acc[8][8];
    #pragma unroll
    for (int i = 0; i < 8; i++)
        #pragma unroll
        for (int j = 0; j < 8; j++) acc[i][j] = 0.f;

    for (int c = 0; c < 8; c++) {
        const int cur = c & 1;
        const bool more = (c < 7);
        if (more) stage_wpq(ew1, (c + 1) << 4, K, st, tid);
        const float (*wb)[256] = wbuf[cur];
        const int kbase = c << 4;
        #pragma unroll
        for (int kk = 0; kk < 16; kk++) {
            const int k = kbase + kk;
            float4 a0 = *(const float4*)&aT[k][r0];
            float4 a1 = *(const float4*)&aT[k][r0 + 4];
            float4 b0 = *(const float4*)&wb[kk][cLo];
            float4 b1 = *(const float4*)&wb[kk][cHi];
            fma88(acc, a0, a1, b0, b1);
        }
        if (more) stage_write(wbuf[cur ^ 1], st, tid);
        __syncthreads();
    }
    #pragma unroll
    for (int i = 0; i < 8; i++) {
        *(float4*)&PQ[(size_t)(row0 + r0 + i) * 256 + cLo] =
            make_float4(acc[i][0], acc[i][1], acc[i][2], acc[i][3]);
        *(float4*)&PQ[(size_t)(row0 + r0 + i) * 256 + cHi] =
            make_float4(acc[i][4], acc[i][5], acc[i][6], acc[i][7]);
    }
}

// ---------------- edge conv ----------------
template<int RGB>
__global__ __launch_bounds__(256) void k_edge(const float* __restrict__ PQ,
    const float* __restrict__ b1, const float* __restrict__ w2,
    const float* __restrict__ b2, const int* __restrict__ nbr,
    float* __restrict__ dout,
    const float* __restrict__ wrgb, const float* __restrict__ brgb,
    float* __restrict__ out)
{
    __shared__ float h1T[128][97];
    __shared__ float wb[32][128];
    const int tid = threadIdx.x;
    const int n0 = blockIdx.x * 32;
    {
        const int c = tid & 127, eg = tid >> 7;
        const float bias = b1[c];
        for (int e = eg; e < 96; e += 2) {
            int n = e / 3;
            int jj = e - n * 3;
            int i = n0 + n;
            int j = nbr[(size_t)i * 3 + jj];
            float v = PQ[(size_t)i * 256 + c] + bias
                    + PQ[(size_t)j * 256 + 128 + c] - PQ[(size_t)i * 256 + 128 + c];
            h1T[c][e] = fmaxf(v, 0.f);
        }
    }
    const int cg = tid & 15, rg = tid >> 4;
    const int cLo = cg * 4, cHi = 64 + cg * 4, e0 = rg * 6;
    float acc[6][8];
    #pragma unroll
    for (int m = 0; m < 6; m++)
        #pragma unroll
        for (int j = 0; j < 8; j++) acc[m][j] = 0.f;
    for (int k0 = 0; k0 < 128; k0 += 32) {
        __syncthreads();
        for (int s = tid; s < 32 * 128; s += 256) {
            int kk = s >> 7, c = s & 127;
            wb[kk][c] = w2[(size_t)(k0 + kk) * 128 + c];
        }
        __syncthreads();
        for (int kk = 0; kk < 32; kk++) {
            const int k = k0 + kk;
            float av[6];
            #pragma unroll
            for (int m = 0; m < 6; m++) av[m] = h1T[k][e0 + m];
            float4 w0v = *(const float4*)&wb[kk][cLo];
            float4 w1v = *(const float4*)&wb[kk][cHi];
            float bv[8] = {w0v.x,w0v.y,w0v.z,w0v.w,w1v.x,w1v.y,w1v.z,w1v.w};
            #pragma unroll
            for (int m = 0; m < 6; m++)
                #pragma unroll
                for (int j = 0; j < 8; j++)
                    acc[m][j] = fmaf(av[m], bv[j], acc[m][j]);
        }
    }
    float bb[8];
    #pragma unroll
    for (int j = 0; j < 8; j++) bb[j] = b2[(j < 4) ? (cLo + j) : (cHi + j - 4)];
    float dA[8], dB[8];
    #pragma unroll
    for (int j = 0; j < 8; j++) {
        float h0 = fmaxf(acc[0][j] + bb[j], 0.f);
        float h1 = fmaxf(acc[1][j] + bb[j], 0.f);
        float h2 = fmaxf(acc[2][j] + bb[j], 0.f);
        float h3 = fmaxf(acc[3][j] + bb[j], 0.f);
        float h4 = fmaxf(acc[4][j] + bb[j], 0.f);
        float h5 = fmaxf(acc[5][j] + bb[j], 0.f);
        dA[j] = (h0 + h1 + h2) * (1.f / 3.f);
        dB[j] = (h3 + h4 + h5) * (1.f / 3.f);
    }
    if (!RGB) {
        *(float4*)&dout[(size_t)(n0 + 2*rg) * 128 + cLo] = make_float4(dA[0], dA[1], dA[2], dA[3]);
        *(float4*)&dout[(size_t)(n0 + 2*rg) * 128 + cHi] = make_float4(dA[4], dA[5], dA[6], dA[7]);
        *(float4*)&dout[(size_t)(n0 + 2*rg + 1) * 128 + cLo] = make_float4(dB[0], dB[1], dB[2], dB[3]);
        *(float4*)&dout[(size_t)(n0 + 2*rg + 1) * 128 + cHi] = make_float4(dB[4], dB[5], dB[6], dB[7]);
    } else {
        __syncthreads();
        float* d2L = &h1T[0][0];
        #pragma unroll
        for (int j = 0; j < 4; j++) {
            d2L[(2*rg)     * 130 + cLo + j] = dA[j];
            d2L[(2*rg)     * 130 + cHi + j] = dA[j + 4];
            d2L[(2*rg + 1) * 130 + cLo + j] = dB[j];
            d2L[(2*rg + 1) * 130 + cHi + j] = dB[j + 4];
        }
        __syncthreads();
        if (tid < 96) {
            int n = tid / 3, ch = tid - 3 * (tid / 3);
            float s = brgb[ch];
            for (int k = 0; k < 128; k++) s = fmaf(d2L[n * 130 + k], wrgb[k * 3 + ch], s);
            out[(size_t)(n0 + n) * 4 + ch] = 1.f / (1.f + expf(-s));
        }
    }
}

// ---------------- launch ----------------
extern "C" void kernel_launch(void* const* d_in, const int* in_sizes, int n_in,
                              void* d_out, int out_size, void* d_ws, size_t ws_size,
                              hipStream_t stream)
{
    const float* x     = (const float*)d_in[0];
    const int*   bid   = (const int*)d_in[1];
    const float* w0    = (const float*)d_in[2];
    const float* b0    = (const float*)d_in[3];
    const float* wmid  = (const float*)d_in[4];
    const float* bmid  = (const float*)d_in[5];
    const float* wskip = (const float*)d_in[6];
    const float* bskip = (const float*)d_in[7];
    const float* wfin  = (const float*)d_in[8];
    const float* bfin  = (const float*)d_in[9];
    const float* wsig  = (const float*)d_in[10];
    const float* bsig  = (const float*)d_in[11];
    const float* e1w1  = (const float*)d_in[12];
    const float* e1b1  = (const float*)d_in[13];
    const float* e1w2  = (const float*)d_in[14];
    const float* e1b2  = (const float*)d_in[15];
    const float* e2w1  = (const float*)d_in[16];
    const float* e2b1  = (const float*)d_in[17];
    const float* e2w2  = (const float*)d_in[18];
    const float* e2b2  = (const float*)d_in[19];
    const float* wrgb  = (const float*)d_in[20];
    const float* brgb  = (const float*)d_in[21];
    float* out = (float*)d_out;

    char* ws = (char*)d_ws;
    int* cnt = (int*)ws;
    int* grp = (int*)(ws + 256);
    int* nbr = (int*)(ws + 256 + NGRP * GSZ * 4);
    float* bufA = (float*)(ws + (1 << 20));                // 41.9 MB
    float* bufB = bufA + (size_t)B_TOTAL * 256;            // 41.9 MB

    // kNN overlays on bufA/bufB heads (dead before trunk/pq writes):
    unsigned short* xbh = (unsigned short*)bufA;
    unsigned short* xbl = xbh + (size_t)B_TOTAL * 64;
    float* cn   = (float*)(xbl + (size_t)B_TOTAL * 64);
    float* pval = cn + B_TOTAL;
    int*   pidx = (int*)(pval + (size_t)B_TOTAL * CPART * 3);
    // trunk weight frags live in bufB tail (2.23 MB at +39 MB; dead before k_pq1 writes PQ)
    unsigned short* wfrag = (unsigned short*)((char*)bufB + ((size_t)39 << 20));

    hipMemsetAsync(cnt, 0, 256, stream);
    k_scatter<<<B_TOTAL / 256, 256, 0, stream>>>(bid, grp, cnt);
    k_wprep<<<(557056 + 255) / 256, 256, 0, stream>>>(w0, wmid, wskip, wfin, wfrag);
    k_gather<<<dim3(GSZ / 128, NGRP), 256, 0, stream>>>(x, grp, xbh, xbl, cn);
    k_knn_mfma<<<dim3(GSZ / 64, CPART, NGRP), 256, 0, stream>>>(xbh, xbl, cn, pval, pidx);
    k_knn_merge<<<(NGRP * GSZ + 255) / 256, 256, 0, stream>>>(pval, pidx, grp, nbr);
    k_trunk_mfma<<<B_TOTAL / 32, 64, 0, stream>>>(x, wfrag, b0, bmid, bskip, bfin,
                                                  wsig, bsig, bufA, out);
    k_pq1<<<B_TOTAL / 64, 256, 0, stream>>>(bufA, x, e1w1, bufB);
    k_edge<0><<<B_TOTAL / 32, 256, 0, stream>>>(bufB, e1b1, e1w2, e1b2, nbr, bufA,
                                                nullptr, nullptr, nullptr);
    k_pq2<<<B_TOTAL / 64, 256, 0, stream>>>(bufA, e2w1, bufB);
    k_edge<1><<<B_TOTAL / 32, 256, 0, stream>>>(bufB, e2b1, e2w2, e2b2, nbr, nullptr,
                                                wrgb, brgb, out);
}

// Round 6
// 1621.357 us; speedup vs baseline: 2.0963x; 1.1011x over previous
//
#include <hip/hip_runtime.h>
#include <hip/hip_bf16.h>
#include <math.h>

#define B_TOTAL 40960
#define NGRP 20
#define GSZ 2048
#define HPAD 68
#define CPART 4

typedef short short8 __attribute__((ext_vector_type(8)));
typedef float f32x4 __attribute__((ext_vector_type(4)));
typedef float f32x16 __attribute__((ext_vector_type(16)));

// ---------------- group scatter ----------------
__global__ void k_scatter(const int* __restrict__ bid, int* __restrict__ grp,
                          int* __restrict__ cnt)
{
    int i = blockIdx.x * 256 + threadIdx.x;
    if (i < B_TOTAL) {
        int g = bid[i];
        int p = atomicAdd(&cnt[g], 1);
        grp[g * GSZ + p] = i;
    }
}

// ---------------- bf16 helpers ----------------
__device__ __forceinline__ unsigned short bf16rne(float v)
{
    unsigned int u = __float_as_uint(v);
    unsigned int r = (u + 0x7FFFu + ((u >> 16) & 1u)) >> 16;
    return (unsigned short)r;
}

__device__ __forceinline__ void splitbf16(const float* v, short8& hi, short8& lo)
{
    #pragma unroll
    for (int j = 0; j < 8; j++) {
        unsigned short h = bf16rne(v[j]);
        hi[j] = (short)h;
        float hf = __uint_as_float((unsigned int)h << 16);
        lo[j] = (short)bf16rne(v[j] - hf);
    }
}

// ---------------- kNN stage 1: gather -> packed bf16 hi/lo planes + norms ----------------
__global__ __launch_bounds__(256) void k_gather(const float* __restrict__ x,
    const int* __restrict__ grp, unsigned short* __restrict__ xbh,
    unsigned short* __restrict__ xbl, float* __restrict__ cn)
{
    __shared__ float tile[128][65];
    __shared__ int ids[128];
    const int tid = threadIdx.x;
    const int g = blockIdx.y;
    const int q0 = blockIdx.x * 128;
    if (tid < 128) ids[tid] = grp[g * GSZ + q0 + tid];
    __syncthreads();
    for (int s = tid; s < 128 * 64; s += 256) {
        int q = s >> 6, d = s & 63;
        tile[q][d] = (d < 63) ? x[(size_t)ids[q] * 90 + d] : 0.f;
    }
    __syncthreads();
    if (tid < 128) {
        float a = 0.f;
        #pragma unroll
        for (int d = 0; d < 63; d++) a = fmaf(tile[tid][d], tile[tid][d], a);
        cn[g * GSZ + q0 + tid] = a;
    }
    for (int s = tid; s < 128 * 32; s += 256) {
        int q = s >> 5, dp = (s & 31) << 1;
        float v0 = tile[q][dp], v1 = tile[q][dp + 1];
        unsigned short h0 = bf16rne(v0), h1 = bf16rne(v1);
        float hf0 = __uint_as_float((unsigned int)h0 << 16);
        float hf1 = __uint_as_float((unsigned int)h1 << 16);
        unsigned short l0 = bf16rne(v0 - hf0), l1 = bf16rne(v1 - hf1);
        size_t pt = (size_t)g * GSZ + q0 + q;
        ((unsigned int*)xbh)[pt * 32 + (dp >> 1)] = (unsigned int)h0 | ((unsigned int)h1 << 16);
        ((unsigned int*)xbl)[pt * 32 + (dp >> 1)] = (unsigned int)l0 | ((unsigned int)l1 << 16);
    }
}

// ---------------- top-3 insert ----------------
__device__ __forceinline__ void ins3(float d, int p,
    float& v0, float& v1, float& v2, int& p0, int& p1, int& p2)
{
    if (d < v0)      { v2 = v1; p2 = p1; v1 = v0; p1 = p0; v0 = d; p0 = p; }
    else if (d < v1) { v2 = v1; p2 = p1; v1 = d;  p1 = p; }
    else if (d < v2) { v2 = d;  p2 = p; }
}

// ---------------- kNN stage 2: MFMA distance tiles, LDS-shared candidate stream ----------------
// grid: (q-tile 0..31, part 0..3, group 0..19); block = 4 waves, wave w -> 16 queries.
// LDS chunk layout: [slot 0..15][cand 0..63][16B]; slot = plane*8 + 16B-subblock of the
// 128B point row. B-frag ds_read_b128 is lane-consecutive-16B -> bank-balanced.
__global__ __launch_bounds__(256) void k_knn_mfma(const unsigned short* __restrict__ xbh,
    const unsigned short* __restrict__ xbl, const float* __restrict__ cn,
    float* __restrict__ pval, int* __restrict__ pidx)
{
    __shared__ char cbuf[2][16384];
    const int tid = threadIdx.x;
    const int lane = tid & 63;
    const int wave = tid >> 6;
    const int g = blockIdx.z;
    const int part = blockIdx.y;
    const int qt0 = blockIdx.x * 64 + wave * 16;
    const size_t gbase = (size_t)g * GSZ;
    const int lp = lane & 15;
    const int kgrp = lane >> 4;        // 0..3
    const int kg = kgrp << 3;

    // A fragments (16 queries per wave), hi/lo planes
    const size_t qb = (gbase + qt0 + lp) * 64;
    short8 ah0 = *(const short8*)(xbh + qb + kg);
    short8 ah1 = *(const short8*)(xbh + qb + 32 + kg);
    short8 al0 = *(const short8*)(xbl + qb + kg);
    short8 al1 = *(const short8*)(xbl + qb + 32 + kg);

    int qpos[4];
    #pragma unroll
    for (int r = 0; r < 4; r++) qpos[r] = qt0 + (kgrp << 2) + r;

    float v0_[4], v1_[4], v2_[4];
    int   p0_[4], p1_[4], p2_[4];
    #pragma unroll
    for (int r = 0; r < 4; r++) {
        v0_[r] = 1e30f; v1_[r] = 1e30f; v2_[r] = 1e30f;
        p0_[r] = 0; p1_[r] = 0; p2_[r] = 0;
    }

    // staging role of this thread: rounds r=0..3 -> slot = r*4 + wave, cand = tid&63
    const int scand = tid & 63;
    const int cbeg = part * (GSZ / CPART);

    short8 st[4];
    #pragma unroll
    for (int r = 0; r < 4; r++) {          // prologue: load chunk 0
        int s = r * 4 + wave;
        const unsigned short* plane = (s < 8) ? xbh : xbl;
        st[r] = *(const short8*)(plane + (gbase + cbeg + scand) * 64 + (s & 7) * 8);
    }
    #pragma unroll
    for (int r = 0; r < 4; r++)
        *(short8*)&cbuf[0][((r * 4 + wave) << 10) + (scand << 4)] = st[r];

    for (int ch = 0; ch < 8; ch++) {
        const int cur = ch & 1;
        __syncthreads();                   // cbuf[cur] ready for all waves
        if (ch < 7) {                      // issue next chunk's loads early (latency hides)
            #pragma unroll
            for (int r = 0; r < 4; r++) {
                int s = r * 4 + wave;
                const unsigned short* plane = (s < 8) ? xbh : xbl;
                st[r] = *(const short8*)(plane +
                        (gbase + cbeg + (ch + 1) * 64 + scand) * 64 + (s & 7) * 8);
            }
        }
        const int cc0 = cbeg + ch * 64;
        #pragma unroll
        for (int ct = 0; ct < 4; ct++) {
            const int coff = ((ct * 16 + lp) << 4);
            short8 bh0 = *(const short8*)&cbuf[cur][((kgrp)      << 10) + coff];
            short8 bh1 = *(const short8*)&cbuf[cur][((4 + kgrp)  << 10) + coff];
            short8 bl0 = *(const short8*)&cbuf[cur][((8 + kgrp)  << 10) + coff];
            short8 bl1 = *(const short8*)&cbuf[cur][((12 + kgrp) << 10) + coff];
            f32x4 acc = {0.f, 0.f, 0.f, 0.f};
            acc = __builtin_amdgcn_mfma_f32_16x16x32_bf16(ah0, bh0, acc, 0, 0, 0);
            acc = __builtin_amdgcn_mfma_f32_16x16x32_bf16(ah1, bh1, acc, 0, 0, 0);
            acc = __builtin_amdgcn_mfma_f32_16x16x32_bf16(al0, bh0, acc, 0, 0, 0);
            acc = __builtin_amdgcn_mfma_f32_16x16x32_bf16(al1, bh1, acc, 0, 0, 0);
            acc = __builtin_amdgcn_mfma_f32_16x16x32_bf16(ah0, bl0, acc, 0, 0, 0);
            acc = __builtin_amdgcn_mfma_f32_16x16x32_bf16(ah1, bl1, acc, 0, 0, 0);
            const float cnv = cn[gbase + cc0 + ct * 16 + lp];
            const int cpos = cc0 + ct * 16 + lp;
            #pragma unroll
            for (int r = 0; r < 4; r++) {
                float val = fmaf(-2.f, acc[r], cnv);
                if (cpos != qpos[r])
                    ins3(val, cpos, v0_[r], v1_[r], v2_[r], p0_[r], p1_[r], p2_[r]);
            }
        }
        if (ch < 7) {
            #pragma unroll
            for (int r = 0; r < 4; r++)
                *(short8*)&cbuf[cur ^ 1][((r * 4 + wave) << 10) + (scand << 4)] = st[r];
        }
    }

    #pragma unroll
    for (int r = 0; r < 4; r++) {
        #pragma unroll
        for (int m = 1; m <= 8; m <<= 1) {
            float o0 = __shfl_xor(v0_[r], m), o1 = __shfl_xor(v1_[r], m), o2 = __shfl_xor(v2_[r], m);
            int   a0 = __shfl_xor(p0_[r], m), a1 = __shfl_xor(p1_[r], m), a2 = __shfl_xor(p2_[r], m);
            ins3(o0, a0, v0_[r], v1_[r], v2_[r], p0_[r], p1_[r], p2_[r]);
            ins3(o1, a1, v0_[r], v1_[r], v2_[r], p0_[r], p1_[r], p2_[r]);
            ins3(o2, a2, v0_[r], v1_[r], v2_[r], p0_[r], p1_[r], p2_[r]);
        }
    }
    if (lp == 0) {
        #pragma unroll
        for (int r = 0; r < 4; r++) {
            size_t off = ((gbase + (size_t)qpos[r]) * CPART + part) * 3;
            pval[off + 0] = v0_[r]; pidx[off + 0] = p0_[r];
            pval[off + 1] = v1_[r]; pidx[off + 1] = p1_[r];
            pval[off + 2] = v2_[r]; pidx[off + 2] = p2_[r];
        }
    }
}

// ---------------- kNN stage 3 ----------------
__global__ void k_knn_merge(const float* __restrict__ pval, const int* __restrict__ pidx,
                            const int* __restrict__ grp, int* __restrict__ nbr)
{
    int t = blockIdx.x * 256 + threadIdx.x;
    if (t >= NGRP * GSZ) return;
    int g = t >> 11;
    float v0 = 1e30f, v1 = 1e30f, v2 = 1e30f;
    int   p0 = 0, p1 = 0, p2 = 0;
    const float* pv = pval + (size_t)t * (CPART * 3);
    const int*   pi = pidx + (size_t)t * (CPART * 3);
    #pragma unroll
    for (int r = 0; r < CPART * 3; r++) ins3(pv[r], pi[r], v0, v1, v2, p0, p1, p2);
    int qi = grp[t];
    nbr[(size_t)qi * 3 + 0] = grp[(g << 11) + p0];
    nbr[(size_t)qi * 3 + 1] = grp[(g << 11) + p1];
    nbr[(size_t)qi * 3 + 2] = grp[(g << 11) + p2];
}

// ---------------- trunk weight prep: split-bf16, fragment-major ----------------
__global__ void k_wprep(const float* __restrict__ w0, const float* __restrict__ wmid,
                        const float* __restrict__ wskip, const float* __restrict__ wfin,
                        unsigned short* __restrict__ wfrag)
{
    int t = blockIdx.x * 256 + threadIdx.x;
    if (t >= 557056) return;
    const int CUMa[10] = {0,4,20,36,52,72,88,104,120,136};
    const int KCa[9]   = {4,16,16,16,20,16,16,16,16};
    int q = t >> 12;
    int L = 0;
    #pragma unroll
    for (int i = 0; i < 9; i++) if (q >= CUMa[i + 1]) L = i + 1;
    int cum = 0, kcn = 16;
    #pragma unroll
    for (int i = 0; i < 9; i++) if (L == i) { cum = CUMa[i]; kcn = KCa[i]; }
    int u = t - (cum << 12);
    int j = u & 7, lane = (u >> 3) & 63;
    int ckk = u >> 9;
    int kc = ckk % kcn, ct = ckk / kcn;
    int col = ct * 32 + (lane & 31);
    int k = kc * 16 + ((lane >> 5) << 3) + j;
    float w;
    if (L == 0)      w = (k < 63)  ? w0[k * 256 + col] : 0.f;
    else if (L == 4) w = (k < 256) ? wskip[(63 + k) * 256 + col]
                       : (k < 319) ? wskip[(k - 256) * 256 + col] : 0.f;
    else if (L == 8) w = wfin[k * 256 + col];
    else {
        int m = (L <= 3) ? (L - 1) : (L - 2);
        w = wmid[(size_t)m * 65536 + k * 256 + col];
    }
    unsigned short hi = bf16rne(w);
    float hf = __uint_as_float((unsigned int)hi << 16);
    unsigned short lo = bf16rne(w - hf);
    size_t base = ((size_t)cum << 13) + (size_t)(ct * kcn + kc) * 1024 + lane * 8 + j;
    wfrag[base] = hi;
    wfrag[base + 512] = lo;
}

// ---------------- fused trunk MLP via split-bf16 MFMA ----------------
template<int KCH, int KCX, int OUTMODE>
__device__ __forceinline__ void mlayer(float (*H)[260], int rowbase,
    const float* __restrict__ x, const unsigned short* __restrict__ wl,
    const float* __restrict__ bias, float* __restrict__ gout, int lane)
{
    const int r31 = lane & 31, g = lane >> 5;
    constexpr int KC = KCH + KCX;
    short8 Ah[KC], Al[KC];
    #pragma unroll
    for (int kc = 0; kc < KCH; kc++) {
        float v[8];
        float4 a = *(const float4*)&H[r31][kc * 16 + g * 8];
        float4 b = *(const float4*)&H[r31][kc * 16 + g * 8 + 4];
        v[0]=a.x; v[1]=a.y; v[2]=a.z; v[3]=a.w; v[4]=b.x; v[5]=b.y; v[6]=b.z; v[7]=b.w;
        splitbf16(v, Ah[kc], Al[kc]);
    }
    #pragma unroll
    for (int t = 0; t < KCX; t++) {
        float v[8];
        #pragma unroll
        for (int j = 0; j < 8; j++) {
            int kx = t * 16 + g * 8 + j;
            v[j] = (kx < 63) ? x[(size_t)(rowbase + r31) * 90 + kx] : 0.f;
        }
        splitbf16(v, Ah[KCH + t], Al[KCH + t]);
    }
    for (int ct = 0; ct < 8; ct++) {
        f32x16 acc;
        #pragma unroll
        for (int r = 0; r < 16; r++) acc[r] = 0.f;
        const unsigned short* wp = wl + (size_t)ct * KC * 1024 + lane * 8;
        #pragma unroll
        for (int kc = 0; kc < KC; kc++) {
            short8 bh = *(const short8*)(wp + kc * 1024);
            short8 bl = *(const short8*)(wp + kc * 1024 + 512);
            acc = __builtin_amdgcn_mfma_f32_32x32x16_bf16(Ah[kc], bh, acc, 0, 0, 0);
            acc = __builtin_amdgcn_mfma_f32_32x32x16_bf16(Al[kc], bh, acc, 0, 0, 0);
            acc = __builtin_amdgcn_mfma_f32_32x32x16_bf16(Ah[kc], bl, acc, 0, 0, 0);
        }
        float bv = bias[ct * 32 + r31];
        #pragma unroll
        for (int r = 0; r < 16; r++) {
            int row = (r & 3) + 8 * (r >> 2) + 4 * g;
            float vv = acc[r] + bv;
            if (OUTMODE == 0) {
                H[row][ct * 32 + r31] = fmaxf(vv, 0.f);
            } else {
                gout[(size_t)(rowbase + row) * 256 + ct * 32 + r31] = vv;
            }
        }
    }
}

__global__ __launch_bounds__(64) void k_trunk_mfma(const float* __restrict__ x,
    const unsigned short* __restrict__ wfrag,
    const float* __restrict__ b0, const float* __restrict__ bmid,
    const float* __restrict__ bskip, const float* __restrict__ bfin,
    const float* __restrict__ wsig, const float* __restrict__ bsig,
    float* __restrict__ feat, float* __restrict__ out)
{
    __shared__ float H[32][260];
    const int lane = threadIdx.x;
    const int rowbase = blockIdx.x * 32;
    const unsigned short* W = wfrag;
    mlayer<0, 4, 0>(H, rowbase, x, W + (size_t)0   * 8192, b0,          nullptr, lane);
    mlayer<16,0, 0>(H, rowbase, x, W + (size_t)4   * 8192, bmid + 0,    nullptr, lane);
    mlayer<16,0, 0>(H, rowbase, x, W + (size_t)20  * 8192, bmid + 256,  nullptr, lane);
    mlayer<16,0, 0>(H, rowbase, x, W + (size_t)36  * 8192, bmid + 512,  nullptr, lane);
    mlayer<16,4, 0>(H, rowbase, x, W + (size_t)52  * 8192, bskip,       nullptr, lane);
    mlayer<16,0, 0>(H, rowbase, x, W + (size_t)72  * 8192, bmid + 768,  nullptr, lane);
    mlayer<16,0, 0>(H, rowbase, x, W + (size_t)88  * 8192, bmid + 1024, nullptr, lane);
    mlayer<16,0, 0>(H, rowbase, x, W + (size_t)104 * 8192, bmid + 1280, nullptr, lane);
    mlayer<16,0, 1>(H, rowbase, x, W + (size_t)120 * 8192, bfin,        feat,    lane);
    const int r31 = lane & 31, g = lane >> 5;
    float s = 0.f;
    #pragma unroll
    for (int kk = 0; kk < 32; kk++) {
        float4 hv = *(const float4*)&H[r31][g * 128 + kk * 4];
        float4 wv = *(const float4*)&wsig[g * 128 + kk * 4];
        s += hv.x * wv.x + hv.y * wv.y + hv.z * wv.z + hv.w * wv.w;
    }
    s += __shfl_xor(s, 32);
    if (lane < 32) out[(size_t)(rowbase + r31) * 4 + 3] = s + bsig[0];
}

// ---------------- helpers for fp32 tile GEMMs (pq/edge) ----------------
__device__ __forceinline__ void fma88(float acc[8][8], float4 a0, float4 a1,
                                      float4 b0, float4 b1)
{
    float av[8] = {a0.x,a0.y,a0.z,a0.w,a1.x,a1.y,a1.z,a1.w};
    float bv[8] = {b0.x,b0.y,b0.z,b0.w,b1.x,b1.y,b1.z,b1.w};
    #pragma unroll
    for (int i = 0; i < 8; i++)
        #pragma unroll
        for (int j = 0; j < 8; j++)
            acc[i][j] = fmaf(av[i], bv[j], acc[i][j]);
}

__device__ __forceinline__ void stage_wpq(const float* __restrict__ ew1, int k0, int K,
                                          float4 st[4], int tid)
{
    #pragma unroll
    for (int u = 0; u < 4; u++) {
        int f = tid + (u << 8);
        int kk = f >> 6, c4 = (f & 63) << 2;
        int k = k0 + kk;
        if (k >= K) st[u] = make_float4(0.f, 0.f, 0.f, 0.f);
        else st[u] = (c4 < 128) ? *(const float4*)&ew1[(size_t)k * 128 + c4]
                                : *(const float4*)&ew1[(size_t)(K + k) * 128 + (c4 - 128)];
    }
}

__device__ __forceinline__ void stage_write(float (*buf)[256], const float4 st[4], int tid)
{
    #pragma unroll
    for (int u = 0; u < 4; u++) {
        int f = tid + (u << 8);
        int kk = f >> 6, c4 = (f & 63) << 2;
        *(float4*)&buf[kk][c4] = st[u];
    }
}

// ---------------- PQ GEMMs for edge convs ----------------
__global__ __launch_bounds__(256) void k_pq1(const float* __restrict__ feat,
    const float* __restrict__ x, const float* __restrict__ ew1,
    float* __restrict__ PQ)
{
    __shared__ float aT[288][HPAD];
    __shared__ float wbuf[2][16][256];
    const int tid = threadIdx.x;
    const int tx = tid & 31, ty = tid >> 5;
    const int cLo = tx * 4, cHi = 128 + tx * 4, r0 = ty * 8;
    const int row0 = blockIdx.x * 64;
    const int K = 283;
    for (int s = tid; s < 64 * 256; s += 256) {
        int r = s >> 8, k = s & 255;
        aT[k][r] = feat[(size_t)(row0 + r) * 256 + k];
    }
    for (int s = tid; s < 32 * 64; s += 256) {
        int dd = s >> 6, r = s & 63;
        aT[256 + dd][r] = (dd < 27) ? x[(size_t)(row0 + r) * 90 + 63 + dd] : 0.f;
    }
    float4 st[4];
    stage_wpq(ew1, 0, K, st, tid);
    __syncthreads();
    stage_write(wbuf[0], st, tid);
    __syncthreads();

    float acc[8][8];
    #pragma unroll
    for (int i = 0; i < 8; i++)
        #pragma unroll
        for (int j = 0; j < 8; j++) acc[i][j] = 0.f;

    const int nch = (K + 15) >> 4;
    for (int c = 0; c < nch; c++) {
        const int cur = c & 1;
        const bool more = (c + 1 < nch);
        if (more) stage_wpq(ew1, (c + 1) << 4, K, st, tid);
        const float (*wb)[256] = wbuf[cur];
        const int kbase = c << 4;
        #pragma unroll
        for (int kk = 0; kk < 16; kk++) {
            const int k = kbase + kk;
            float4 a0 = *(const float4*)&aT[k][r0];
            float4 a1 = *(const float4*)&aT[k][r0 + 4];
            float4 b0 = *(const float4*)&wb[kk][cLo];
            float4 b1 = *(const float4*)&wb[kk][cHi];
            fma88(acc, a0, a1, b0, b1);
        }
        if (more) stage_write(wbuf[cur ^ 1], st, tid);
        __syncthreads();
    }
    #pragma unroll
    for (int i = 0; i < 8; i++) {
        *(float4*)&PQ[(size_t)(row0 + r0 + i) * 256 + cLo] =
            make_float4(acc[i][0], acc[i][1], acc[i][2], acc[i][3]);
        *(float4*)&PQ[(size_t)(row0 + r0 + i) * 256 + cHi] =
            make_float4(acc[i][4], acc[i][5], acc[i][6], acc[i][7]);
    }
}

__global__ __launch_bounds__(256) void k_pq2(const float* __restrict__ d1,
    const float* __restrict__ ew1, float* __restrict__ PQ)
{
    __shared__ float aT[128][HPAD];
    __shared__ float wbuf[2][16][256];
    const int tid = threadIdx.x;
    const int tx = tid & 31, ty = tid >> 5;
    const int cLo = tx * 4, cHi = 128 + tx * 4, r0 = ty * 8;
    const int row0 = blockIdx.x * 64;
    const int K = 128;
    for (int s = tid; s < 64 * 128; s += 256) {
        int r = s >> 7, k = s & 127;
        aT[k][r] = d1[(size_t)(row0 + r) * 128 + k];
    }
    float4 st[4];
    stage_wpq(ew1, 0, K, st, tid);
    __syncthreads();
    stage_write(wbuf[0], st, tid);
    __syncthreads();

    float acc[8][8];
    #pragma unroll
    for (int i = 0; i < 8; i++)
        #pragma unroll
        for (int j = 0; j < 8; j++) acc[i][j] = 0.f;

    for (int c = 0; c < 8; c++) {
        const int cur = c & 1;
        const bool more = (c < 7);
        if (more) stage_wpq(ew1, (c + 1) << 4, K, st, tid);
        const float (*wb)[256] = wbuf[cur];
        const int kbase = c << 4;
        #pragma unroll
        for (int kk = 0; kk < 16; kk++) {
            const int k = kbase + kk;
            float4 a0 = *(const float4*)&aT[k][r0];
            float4 a1 = *(const float4*)&aT[k][r0 + 4];
            float4 b0 = *(const float4*)&wb[kk][cLo];
            float4 b1 = *(const float4*)&wb[kk][cHi];
            fma88(acc, a0, a1, b0, b1);
        }
        if (more) stage_write(wbuf[cur ^ 1], st, tid);
        __syncthreads();
    }
    #pragma unroll
    for (int i = 0; i < 8; i++) {
        *(float4*)&PQ[(size_t)(row0 + r0 + i) * 256 + cLo] =
            make_float4(acc[i][0], acc[i][1], acc[i][2], acc[i][3]);
        *(float4*)&PQ[(size_t)(row0 + r0 + i) * 256 + cHi] =
            make_float4(acc[i][4], acc[i][5], acc[i][6], acc[i][7]);
    }
}

// ---------------- edge conv ----------------
template<int RGB>
__global__ __launch_bounds__(256) void k_edge(const float* __restrict__ PQ,
    const float* __restrict__ b1, const float* __restrict__ w2,
    const float* __restrict__ b2, const int* __restrict__ nbr,
    float* __restrict__ dout,
    const float* __restrict__ wrgb, const float* __restrict__ brgb,
    float* __restrict__ out)
{
    __shared__ float h1T[128][97];
    __shared__ float wb[32][128];
    const int tid = threadIdx.x;
    const int n0 = blockIdx.x * 32;
    {
        const int c = tid & 127, eg = tid >> 7;
        const float bias = b1[c];
        for (int e = eg; e < 96; e += 2) {
            int n = e / 3;
            int jj = e - n * 3;
            int i = n0 + n;
            int j = nbr[(size_t)i * 3 + jj];
            float v = PQ[(size_t)i * 256 + c] + bias
                    + PQ[(size_t)j * 256 + 128 + c] - PQ[(size_t)i * 256 + 128 + c];
            h1T[c][e] = fmaxf(v, 0.f);
        }
    }
    const int cg = tid & 15, rg = tid >> 4;
    const int cLo = cg * 4, cHi = 64 + cg * 4, e0 = rg * 6;
    float acc[6][8];
    #pragma unroll
    for (int m = 0; m < 6; m++)
        #pragma unroll
        for (int j = 0; j < 8; j++) acc[m][j] = 0.f;
    for (int k0 = 0; k0 < 128; k0 += 32) {
        __syncthreads();
        for (int s = tid; s < 32 * 128; s += 256) {
            int kk = s >> 7, c = s & 127;
            wb[kk][c] = w2[(size_t)(k0 + kk) * 128 + c];
        }
        __syncthreads();
        for (int kk = 0; kk < 32; kk++) {
            const int k = k0 + kk;
            float av[6];
            #pragma unroll
            for (int m = 0; m < 6; m++) av[m] = h1T[k][e0 + m];
            float4 w0v = *(const float4*)&wb[kk][cLo];
            float4 w1v = *(const float4*)&wb[kk][cHi];
            float bv[8] = {w0v.x,w0v.y,w0v.z,w0v.w,w1v.x,w1v.y,w1v.z,w1v.w};
            #pragma unroll
            for (int m = 0; m < 6; m++)
                #pragma unroll
                for (int j = 0; j < 8; j++)
                    acc[m][j] = fmaf(av[m], bv[j], acc[m][j]);
        }
    }
    float bb[8];
    #pragma unroll
    for (int j = 0; j < 8; j++) bb[j] = b2[(j < 4) ? (cLo + j) : (cHi + j - 4)];
    float dA[8], dB[8];
    #pragma unroll
    for (int j = 0; j < 8; j++) {
        float h0 = fmaxf(acc[0][j] + bb[j], 0.f);
        float h1 = fmaxf(acc[1][j] + bb[j], 0.f);
        float h2 = fmaxf(acc[2][j] + bb[j], 0.f);
        float h3 = fmaxf(acc[3][j] + bb[j], 0.f);
        float h4 = fmaxf(acc[4][j] + bb[j], 0.f);
        float h5 = fmaxf(acc[5][j] + bb[j], 0.f);
        dA[j] = (h0 + h1 + h2) * (1.f / 3.f);
        dB[j] = (h3 + h4 + h5) * (1.f / 3.f);
    }
    if (!RGB) {
        *(float4*)&dout[(size_t)(n0 + 2*rg) * 128 + cLo] = make_float4(dA[0], dA[1], dA[2], dA[3]);
        *(float4*)&dout[(size_t)(n0 + 2*rg) * 128 + cHi] = make_float4(dA[4], dA[5], dA[6], dA[7]);
        *(float4*)&dout[(size_t)(n0 + 2*rg + 1) * 128 + cLo] = make_float4(dB[0], dB[1], dB[2], dB[3]);
        *(float4*)&dout[(size_t)(n0 + 2*rg + 1) * 128 + cHi] = make_float4(dB[4], dB[5], dB[6], dB[7]);
    } else {
        __syncthreads();
        float* d2L = &h1T[0][0];
        #pragma unroll
        for (int j = 0; j < 4; j++) {
            d2L[(2*rg)     * 130 + cLo + j] = dA[j];
            d2L[(2*rg)     * 130 + cHi + j] = dA[j + 4];
            d2L[(2*rg + 1) * 130 + cLo + j] = dB[j];
            d2L[(2*rg + 1) * 130 + cHi + j] = dB[j + 4];
        }
        __syncthreads();
        if (tid < 96) {
            int n = tid / 3, ch = tid - 3 * (tid / 3);
            float s = brgb[ch];
            for (int k = 0; k < 128; k++) s = fmaf(d2L[n * 130 + k], wrgb[k * 3 + ch], s);
            out[(size_t)(n0 + n) * 4 + ch] = 1.f / (1.f + expf(-s));
        }
    }
}

// ---------------- launch ----------------
extern "C" void kernel_launch(void* const* d_in, const int* in_sizes, int n_in,
                              void* d_out, int out_size, void* d_ws, size_t ws_size,
                              hipStream_t stream)
{
    const float* x     = (const float*)d_in[0];
    const int*   bid   = (const int*)d_in[1];
    const float* w0    = (const float*)d_in[2];
    const float* b0    = (const float*)d_in[3];
    const float* wmid  = (const float*)d_in[4];
    const float* bmid  = (const float*)d_in[5];
    const float* wskip = (const float*)d_in[6];
    const float* bskip = (const float*)d_in[7];
    const float* wfin  = (const float*)d_in[8];
    const float* bfin  = (const float*)d_in[9];
    const float* wsig  = (const float*)d_in[10];
    const float* bsig  = (const float*)d_in[11];
    const float* e1w1  = (const float*)d_in[12];
    const float* e1b1  = (const float*)d_in[13];
    const float* e1w2  = (const float*)d_in[14];
    const float* e1b2  = (const float*)d_in[15];
    const float* e2w1  = (const float*)d_in[16];
    const float* e2b1  = (const float*)d_in[17];
    const float* e2w2  = (const float*)d_in[18];
    const float* e2b2  = (const float*)d_in[19];
    const float* wrgb  = (const float*)d_in[20];
    const float* brgb  = (const float*)d_in[21];
    float* out = (float*)d_out;

    char* ws = (char*)d_ws;
    int* cnt = (int*)ws;
    int* grp = (int*)(ws + 256);
    int* nbr = (int*)(ws + 256 + NGRP * GSZ * 4);
    float* bufA = (float*)(ws + (1 << 20));                // 41.9 MB
    float* bufB = bufA + (size_t)B_TOTAL * 256;            // 41.9 MB

    unsigned short* xbh = (unsigned short*)bufA;
    unsigned short* xbl = xbh + (size_t)B_TOTAL * 64;
    float* cn   = (float*)(xbl + (size_t)B_TOTAL * 64);
    float* pval = cn + B_TOTAL;
    int*   pidx = (int*)(pval + (size_t)B_TOTAL * CPART * 3);
    unsigned short* wfrag = (unsigned short*)((char*)bufB + ((size_t)39 << 20));

    hipMemsetAsync(cnt, 0, 256, stream);
    k_scatter<<<B_TOTAL / 256, 256, 0, stream>>>(bid, grp, cnt);
    k_wprep<<<(557056 + 255) / 256, 256, 0, stream>>>(w0, wmid, wskip, wfin, wfrag);
    k_gather<<<dim3(GSZ / 128, NGRP), 256, 0, stream>>>(x, grp, xbh, xbl, cn);
    k_knn_mfma<<<dim3(GSZ / 64, CPART, NGRP), 256, 0, stream>>>(xbh, xbl, cn, pval, pidx);
    k_knn_merge<<<(NGRP * GSZ + 255) / 256, 256, 0, stream>>>(pval, pidx, grp, nbr);
    k_trunk_mfma<<<B_TOTAL / 32, 64, 0, stream>>>(x, wfrag, b0, bmid, bskip, bfin,
                                                  wsig, bsig, bufA, out);
    k_pq1<<<B_TOTAL / 64, 256, 0, stream>>>(bufA, x, e1w1, bufB);
    k_edge<0><<<B_TOTAL / 32, 256, 0, stream>>>(bufB, e1b1, e1w2, e1b2, nbr, bufA,
                                                nullptr, nullptr, nullptr);
    k_pq2<<<B_TOTAL / 64, 256, 0, stream>>>(bufA, e2w1, bufB);
    k_edge<1><<<B_TOTAL / 32, 256, 0, stream>>>(bufB, e2b1, e2w2, e2b2, nbr, nullptr,
                                                wrgb, brgb, out);
}

// Round 7
// 1159.140 us; speedup vs baseline: 2.9322x; 1.3988x over previous
//
#include <hip/hip_runtime.h>
#include <hip/hip_bf16.h>
#include <math.h>

#define B_TOTAL 40960
#define NGRP 20
#define GSZ 2048
#define HPAD 68
#define CPART 4

typedef short short8 __attribute__((ext_vector_type(8)));
typedef short short4v __attribute__((ext_vector_type(4)));
typedef float f32x4 __attribute__((ext_vector_type(4)));
typedef float f32x16 __attribute__((ext_vector_type(16)));

// ---------------- group scatter ----------------
__global__ void k_scatter(const int* __restrict__ bid, int* __restrict__ grp,
                          int* __restrict__ cnt)
{
    int i = blockIdx.x * 256 + threadIdx.x;
    if (i < B_TOTAL) {
        int g = bid[i];
        int p = atomicAdd(&cnt[g], 1);
        grp[g * GSZ + p] = i;
    }
}

// ---------------- bf16 helpers ----------------
__device__ __forceinline__ unsigned short bf16rne(float v)
{
    unsigned int u = __float_as_uint(v);
    unsigned int r = (u + 0x7FFFu + ((u >> 16) & 1u)) >> 16;
    return (unsigned short)r;
}

__device__ __forceinline__ float bf2f(unsigned short h)
{
    return __uint_as_float((unsigned int)h << 16);
}

__device__ __forceinline__ void splitbf16(const float* v, short8& hi, short8& lo)
{
    #pragma unroll
    for (int j = 0; j < 8; j++) {
        unsigned short h = bf16rne(v[j]);
        hi[j] = (short)h;
        lo[j] = (short)bf16rne(v[j] - bf2f(h));
    }
}

// ---------------- kNN stage 1: gather -> packed bf16 hi/lo planes + norms ----------------
__global__ __launch_bounds__(256) void k_gather(const float* __restrict__ x,
    const int* __restrict__ grp, unsigned short* __restrict__ xbh,
    unsigned short* __restrict__ xbl, float* __restrict__ cn)
{
    __shared__ float tile[128][65];
    __shared__ int ids[128];
    const int tid = threadIdx.x;
    const int g = blockIdx.y;
    const int q0 = blockIdx.x * 128;
    if (tid < 128) ids[tid] = grp[g * GSZ + q0 + tid];
    __syncthreads();
    for (int s = tid; s < 128 * 64; s += 256) {
        int q = s >> 6, d = s & 63;
        tile[q][d] = (d < 63) ? x[(size_t)ids[q] * 90 + d] : 0.f;
    }
    __syncthreads();
    if (tid < 128) {
        float a = 0.f;
        #pragma unroll
        for (int d = 0; d < 63; d++) a = fmaf(tile[tid][d], tile[tid][d], a);
        cn[g * GSZ + q0 + tid] = a;
    }
    for (int s = tid; s < 128 * 32; s += 256) {
        int q = s >> 5, dp = (s & 31) << 1;
        float v0 = tile[q][dp], v1 = tile[q][dp + 1];
        unsigned short h0 = bf16rne(v0), h1 = bf16rne(v1);
        unsigned short l0 = bf16rne(v0 - bf2f(h0)), l1 = bf16rne(v1 - bf2f(h1));
        size_t pt = (size_t)g * GSZ + q0 + q;
        ((unsigned int*)xbh)[pt * 32 + (dp >> 1)] = (unsigned int)h0 | ((unsigned int)h1 << 16);
        ((unsigned int*)xbl)[pt * 32 + (dp >> 1)] = (unsigned int)l0 | ((unsigned int)l1 << 16);
    }
}

// ---------------- top-3 insert ----------------
__device__ __forceinline__ void ins3(float d, int p,
    float& v0, float& v1, float& v2, int& p0, int& p1, int& p2)
{
    if (d < v0)      { v2 = v1; p2 = p1; v1 = v0; p1 = p0; v0 = d; p0 = p; }
    else if (d < v1) { v2 = v1; p2 = p1; v1 = d;  p1 = p; }
    else if (d < v2) { v2 = d;  p2 = p; }
}

// ---------------- kNN stage 2: MFMA distance tiles, LDS-shared candidate stream ----------------
__global__ __launch_bounds__(256) void k_knn_mfma(const unsigned short* __restrict__ xbh,
    const unsigned short* __restrict__ xbl, const float* __restrict__ cn,
    float* __restrict__ pval, int* __restrict__ pidx)
{
    __shared__ char cbuf[2][16384];
    const int tid = threadIdx.x;
    const int lane = tid & 63;
    const int wave = tid >> 6;
    const int g = blockIdx.z;
    const int part = blockIdx.y;
    const int qt0 = blockIdx.x * 64 + wave * 16;
    const size_t gbase = (size_t)g * GSZ;
    const int lp = lane & 15;
    const int kgrp = lane >> 4;
    const int kg = kgrp << 3;

    const size_t qb = (gbase + qt0 + lp) * 64;
    short8 ah0 = *(const short8*)(xbh + qb + kg);
    short8 ah1 = *(const short8*)(xbh + qb + 32 + kg);
    short8 al0 = *(const short8*)(xbl + qb + kg);
    short8 al1 = *(const short8*)(xbl + qb + 32 + kg);

    int qpos[4];
    #pragma unroll
    for (int r = 0; r < 4; r++) qpos[r] = qt0 + (kgrp << 2) + r;

    float v0_[4], v1_[4], v2_[4];
    int   p0_[4], p1_[4], p2_[4];
    #pragma unroll
    for (int r = 0; r < 4; r++) {
        v0_[r] = 1e30f; v1_[r] = 1e30f; v2_[r] = 1e30f;
        p0_[r] = 0; p1_[r] = 0; p2_[r] = 0;
    }

    const int scand = tid & 63;
    const int cbeg = part * (GSZ / CPART);

    short8 st[4];
    #pragma unroll
    for (int r = 0; r < 4; r++) {
        int s = r * 4 + wave;
        const unsigned short* plane = (s < 8) ? xbh : xbl;
        st[r] = *(const short8*)(plane + (gbase + cbeg + scand) * 64 + (s & 7) * 8);
    }
    #pragma unroll
    for (int r = 0; r < 4; r++)
        *(short8*)&cbuf[0][((r * 4 + wave) << 10) + (scand << 4)] = st[r];

    for (int ch = 0; ch < 8; ch++) {
        const int cur = ch & 1;
        __syncthreads();
        if (ch < 7) {
            #pragma unroll
            for (int r = 0; r < 4; r++) {
                int s = r * 4 + wave;
                const unsigned short* plane = (s < 8) ? xbh : xbl;
                st[r] = *(const short8*)(plane +
                        (gbase + cbeg + (ch + 1) * 64 + scand) * 64 + (s & 7) * 8);
            }
        }
        const int cc0 = cbeg + ch * 64;
        #pragma unroll
        for (int ct = 0; ct < 4; ct++) {
            const int coff = ((ct * 16 + lp) << 4);
            short8 bh0 = *(const short8*)&cbuf[cur][((kgrp)      << 10) + coff];
            short8 bh1 = *(const short8*)&cbuf[cur][((4 + kgrp)  << 10) + coff];
            short8 bl0 = *(const short8*)&cbuf[cur][((8 + kgrp)  << 10) + coff];
            short8 bl1 = *(const short8*)&cbuf[cur][((12 + kgrp) << 10) + coff];
            f32x4 acc = {0.f, 0.f, 0.f, 0.f};
            acc = __builtin_amdgcn_mfma_f32_16x16x32_bf16(ah0, bh0, acc, 0, 0, 0);
            acc = __builtin_amdgcn_mfma_f32_16x16x32_bf16(ah1, bh1, acc, 0, 0, 0);
            acc = __builtin_amdgcn_mfma_f32_16x16x32_bf16(al0, bh0, acc, 0, 0, 0);
            acc = __builtin_amdgcn_mfma_f32_16x16x32_bf16(al1, bh1, acc, 0, 0, 0);
            acc = __builtin_amdgcn_mfma_f32_16x16x32_bf16(ah0, bl0, acc, 0, 0, 0);
            acc = __builtin_amdgcn_mfma_f32_16x16x32_bf16(ah1, bl1, acc, 0, 0, 0);
            const float cnv = cn[gbase + cc0 + ct * 16 + lp];
            const int cpos = cc0 + ct * 16 + lp;
            #pragma unroll
            for (int r = 0; r < 4; r++) {
                float val = fmaf(-2.f, acc[r], cnv);
                if (cpos != qpos[r])
                    ins3(val, cpos, v0_[r], v1_[r], v2_[r], p0_[r], p1_[r], p2_[r]);
            }
        }
        if (ch < 7) {
            #pragma unroll
            for (int r = 0; r < 4; r++)
                *(short8*)&cbuf[cur ^ 1][((r * 4 + wave) << 10) + (scand << 4)] = st[r];
        }
    }

    #pragma unroll
    for (int r = 0; r < 4; r++) {
        #pragma unroll
        for (int m = 1; m <= 8; m <<= 1) {
            float o0 = __shfl_xor(v0_[r], m), o1 = __shfl_xor(v1_[r], m), o2 = __shfl_xor(v2_[r], m);
            int   a0 = __shfl_xor(p0_[r], m), a1 = __shfl_xor(p1_[r], m), a2 = __shfl_xor(p2_[r], m);
            ins3(o0, a0, v0_[r], v1_[r], v2_[r], p0_[r], p1_[r], p2_[r]);
            ins3(o1, a1, v0_[r], v1_[r], v2_[r], p0_[r], p1_[r], p2_[r]);
            ins3(o2, a2, v0_[r], v1_[r], v2_[r], p0_[r], p1_[r], p2_[r]);
        }
    }
    if (lp == 0) {
        #pragma unroll
        for (int r = 0; r < 4; r++) {
            size_t off = ((gbase + (size_t)qpos[r]) * CPART + part) * 3;
            pval[off + 0] = v0_[r]; pidx[off + 0] = p0_[r];
            pval[off + 1] = v1_[r]; pidx[off + 1] = p1_[r];
            pval[off + 2] = v2_[r]; pidx[off + 2] = p2_[r];
        }
    }
}

// ---------------- kNN stage 3 ----------------
__global__ void k_knn_merge(const float* __restrict__ pval, const int* __restrict__ pidx,
                            const int* __restrict__ grp, int* __restrict__ nbr)
{
    int t = blockIdx.x * 256 + threadIdx.x;
    if (t >= NGRP * GSZ) return;
    int g = t >> 11;
    float v0 = 1e30f, v1 = 1e30f, v2 = 1e30f;
    int   p0 = 0, p1 = 0, p2 = 0;
    const float* pv = pval + (size_t)t * (CPART * 3);
    const int*   pi = pidx + (size_t)t * (CPART * 3);
    #pragma unroll
    for (int r = 0; r < CPART * 3; r++) ins3(pv[r], pi[r], v0, v1, v2, p0, p1, p2);
    int qi = grp[t];
    nbr[(size_t)qi * 3 + 0] = grp[(g << 11) + p0];
    nbr[(size_t)qi * 3 + 1] = grp[(g << 11) + p1];
    nbr[(size_t)qi * 3 + 2] = grp[(g << 11) + p2];
}

// ---------------- trunk weight prep: split-bf16, fragment-major ----------------
__global__ void k_wprep(const float* __restrict__ w0, const float* __restrict__ wmid,
                        const float* __restrict__ wskip, const float* __restrict__ wfin,
                        unsigned short* __restrict__ wfrag)
{
    int t = blockIdx.x * 256 + threadIdx.x;
    if (t >= 557056) return;
    const int CUMa[10] = {0,4,20,36,52,72,88,104,120,136};
    const int KCa[9]   = {4,16,16,16,20,16,16,16,16};
    int q = t >> 12;
    int L = 0;
    #pragma unroll
    for (int i = 0; i < 9; i++) if (q >= CUMa[i + 1]) L = i + 1;
    int cum = 0, kcn = 16;
    #pragma unroll
    for (int i = 0; i < 9; i++) if (L == i) { cum = CUMa[i]; kcn = KCa[i]; }
    int u = t - (cum << 12);
    int j = u & 7, lane = (u >> 3) & 63;
    int ckk = u >> 9;
    int kc = ckk % kcn, ct = ckk / kcn;
    int col = ct * 32 + (lane & 31);
    int k = kc * 16 + ((lane >> 5) << 3) + j;
    float w;
    if (L == 0)      w = (k < 63)  ? w0[k * 256 + col] : 0.f;
    else if (L == 4) w = (k < 256) ? wskip[(63 + k) * 256 + col]
                       : (k < 319) ? wskip[(k - 256) * 256 + col] : 0.f;
    else if (L == 8) w = wfin[k * 256 + col];
    else {
        int m = (L <= 3) ? (L - 1) : (L - 2);
        w = wmid[(size_t)m * 65536 + k * 256 + col];
    }
    unsigned short hi = bf16rne(w);
    unsigned short lo = bf16rne(w - bf2f(hi));
    size_t base = ((size_t)cum << 13) + (size_t)(ct * kcn + kc) * 1024 + lane * 8 + j;
    wfrag[base] = hi;
    wfrag[base + 512] = lo;
}

// ---------------- fused trunk MLP: 4 waves share one 32-row tile, split-bf16 H in LDS ----------------
// Hh/Hl: [32 rows][264] bf16 planes. Wave w computes column tiles ct = 2w, 2w+1.
template<int KCH, int KCX, int OUTMODE>
__device__ __forceinline__ void mlayer(unsigned short (*Hh)[264], unsigned short (*Hl)[264],
    int rowbase, const float* __restrict__ x, const unsigned short* __restrict__ wl,
    const float* __restrict__ bias, float* __restrict__ gout, int lane, int wave)
{
    const int r31 = lane & 31, g = lane >> 5;
    constexpr int KC = KCH + KCX;
    short8 xh[KCX > 0 ? KCX : 1], xl[KCX > 0 ? KCX : 1];
    if (KCX > 0) {
        #pragma unroll
        for (int t = 0; t < KCX; t++) {
            float v[8];
            #pragma unroll
            for (int j = 0; j < 8; j++) {
                int kx = t * 16 + g * 8 + j;
                v[j] = (kx < 63) ? x[(size_t)(rowbase + r31) * 90 + kx] : 0.f;
            }
            splitbf16(v, xh[t], xl[t]);
        }
    }
    const int ct0 = wave * 2;
    f32x16 acc0, acc1;
    #pragma unroll
    for (int r = 0; r < 16; r++) { acc0[r] = 0.f; acc1[r] = 0.f; }
    const unsigned short* wp0 = wl + (size_t)ct0 * KC * 1024 + lane * 8;
    const unsigned short* wp1 = wp0 + (size_t)KC * 1024;
    #pragma unroll
    for (int kc = 0; kc < KCH; kc++) {
        short8 ah = *(const short8*)&Hh[r31][kc * 16 + g * 8];
        short8 al = *(const short8*)&Hl[r31][kc * 16 + g * 8];
        short8 b0h = *(const short8*)(wp0 + kc * 1024);
        short8 b0l = *(const short8*)(wp0 + kc * 1024 + 512);
        short8 b1h = *(const short8*)(wp1 + kc * 1024);
        short8 b1l = *(const short8*)(wp1 + kc * 1024 + 512);
        acc0 = __builtin_amdgcn_mfma_f32_32x32x16_bf16(ah, b0h, acc0, 0, 0, 0);
        acc1 = __builtin_amdgcn_mfma_f32_32x32x16_bf16(ah, b1h, acc1, 0, 0, 0);
        acc0 = __builtin_amdgcn_mfma_f32_32x32x16_bf16(al, b0h, acc0, 0, 0, 0);
        acc1 = __builtin_amdgcn_mfma_f32_32x32x16_bf16(al, b1h, acc1, 0, 0, 0);
        acc0 = __builtin_amdgcn_mfma_f32_32x32x16_bf16(ah, b0l, acc0, 0, 0, 0);
        acc1 = __builtin_amdgcn_mfma_f32_32x32x16_bf16(ah, b1l, acc1, 0, 0, 0);
    }
    #pragma unroll
    for (int t = 0; t < KCX; t++) {
        const int kc = KCH + t;
        short8 b0h = *(const short8*)(wp0 + kc * 1024);
        short8 b0l = *(const short8*)(wp0 + kc * 1024 + 512);
        short8 b1h = *(const short8*)(wp1 + kc * 1024);
        short8 b1l = *(const short8*)(wp1 + kc * 1024 + 512);
        acc0 = __builtin_amdgcn_mfma_f32_32x32x16_bf16(xh[t], b0h, acc0, 0, 0, 0);
        acc1 = __builtin_amdgcn_mfma_f32_32x32x16_bf16(xh[t], b1h, acc1, 0, 0, 0);
        acc0 = __builtin_amdgcn_mfma_f32_32x32x16_bf16(xl[t], b0h, acc0, 0, 0, 0);
        acc1 = __builtin_amdgcn_mfma_f32_32x32x16_bf16(xl[t], b1h, acc1, 0, 0, 0);
        acc0 = __builtin_amdgcn_mfma_f32_32x32x16_bf16(xh[t], b0l, acc0, 0, 0, 0);
        acc1 = __builtin_amdgcn_mfma_f32_32x32x16_bf16(xh[t], b1l, acc1, 0, 0, 0);
    }
    const float bv0 = bias[ct0 * 32 + r31];
    const float bv1 = bias[ct0 * 32 + 32 + r31];
    if (OUTMODE == 0) {
        __syncthreads();                    // all waves done reading H
        #pragma unroll
        for (int r = 0; r < 16; r++) {
            int row = (r & 3) + 8 * (r >> 2) + 4 * g;
            float v0 = fmaxf(acc0[r] + bv0, 0.f);
            float v1 = fmaxf(acc1[r] + bv1, 0.f);
            unsigned short h0 = bf16rne(v0), h1 = bf16rne(v1);
            Hh[row][ct0 * 32 + r31] = h0;
            Hl[row][ct0 * 32 + r31] = bf16rne(v0 - bf2f(h0));
            Hh[row][ct0 * 32 + 32 + r31] = h1;
            Hl[row][ct0 * 32 + 32 + r31] = bf16rne(v1 - bf2f(h1));
        }
        __syncthreads();                    // H ready for next layer
    } else {
        #pragma unroll
        for (int r = 0; r < 16; r++) {
            int row = (r & 3) + 8 * (r >> 2) + 4 * g;
            gout[(size_t)(rowbase + row) * 256 + ct0 * 32 + r31] = acc0[r] + bv0;
            gout[(size_t)(rowbase + row) * 256 + ct0 * 32 + 32 + r31] = acc1[r] + bv1;
        }
    }
}

__global__ __launch_bounds__(256, 4) void k_trunk_mfma(const float* __restrict__ x,
    const unsigned short* __restrict__ wfrag,
    const float* __restrict__ b0, const float* __restrict__ bmid,
    const float* __restrict__ bskip, const float* __restrict__ bfin,
    const float* __restrict__ wsig, const float* __restrict__ bsig,
    float* __restrict__ feat, float* __restrict__ out)
{
    __shared__ unsigned short Hh[32][264];
    __shared__ unsigned short Hl[32][264];
    const int lane = threadIdx.x & 63;
    const int wave = threadIdx.x >> 6;
    const int rowbase = blockIdx.x * 32;
    const unsigned short* W = wfrag;
    mlayer<0, 4, 0>(Hh, Hl, rowbase, x, W + (size_t)0   * 8192, b0,          nullptr, lane, wave);
    mlayer<16,0, 0>(Hh, Hl, rowbase, x, W + (size_t)4   * 8192, bmid + 0,    nullptr, lane, wave);
    mlayer<16,0, 0>(Hh, Hl, rowbase, x, W + (size_t)20  * 8192, bmid + 256,  nullptr, lane, wave);
    mlayer<16,0, 0>(Hh, Hl, rowbase, x, W + (size_t)36  * 8192, bmid + 512,  nullptr, lane, wave);
    mlayer<16,4, 0>(Hh, Hl, rowbase, x, W + (size_t)52  * 8192, bskip,       nullptr, lane, wave);
    mlayer<16,0, 0>(Hh, Hl, rowbase, x, W + (size_t)72  * 8192, bmid + 768,  nullptr, lane, wave);
    mlayer<16,0, 0>(Hh, Hl, rowbase, x, W + (size_t)88  * 8192, bmid + 1024, nullptr, lane, wave);
    mlayer<16,0, 0>(Hh, Hl, rowbase, x, W + (size_t)104 * 8192, bmid + 1280, nullptr, lane, wave);
    mlayer<16,0, 1>(Hh, Hl, rowbase, x, W + (size_t)120 * 8192, bfin,        feat,    lane, wave);
    if (wave == 0) {   // sigma from layer-7 H (still intact; last write barrier passed)
        const int r31 = lane & 31, g = lane >> 5;
        float s = 0.f;
        #pragma unroll
        for (int kk = 0; kk < 32; kk++) {
            short4v hh = *(const short4v*)&Hh[r31][g * 128 + kk * 4];
            short4v hl = *(const short4v*)&Hl[r31][g * 128 + kk * 4];
            float4 wv = *(const float4*)&wsig[g * 128 + kk * 4];
            s = fmaf(bf2f((unsigned short)hh[0]) + bf2f((unsigned short)hl[0]), wv.x, s);
            s = fmaf(bf2f((unsigned short)hh[1]) + bf2f((unsigned short)hl[1]), wv.y, s);
            s = fmaf(bf2f((unsigned short)hh[2]) + bf2f((unsigned short)hl[2]), wv.z, s);
            s = fmaf(bf2f((unsigned short)hh[3]) + bf2f((unsigned short)hl[3]), wv.w, s);
        }
        s += __shfl_xor(s, 32);
        if (lane < 32) out[(size_t)(rowbase + r31) * 4 + 3] = s + bsig[0];
    }
}

// ---------------- helpers for fp32 tile GEMMs (pq/edge) ----------------
__device__ __forceinline__ void fma88(float acc[8][8], float4 a0, float4 a1,
                                      float4 b0, float4 b1)
{
    float av[8] = {a0.x,a0.y,a0.z,a0.w,a1.x,a1.y,a1.z,a1.w};
    float bv[8] = {b0.x,b0.y,b0.z,b0.w,b1.x,b1.y,b1.z,b1.w};
    #pragma unroll
    for (int i = 0; i < 8; i++)
        #pragma unroll
        for (int j = 0; j < 8; j++)
            acc[i][j] = fmaf(av[i], bv[j], acc[i][j]);
}

__device__ __forceinline__ void stage_wpq(const float* __restrict__ ew1, int k0, int K,
                                          float4 st[4], int tid)
{
    #pragma unroll
    for (int u = 0; u < 4; u++) {
        int f = tid + (u << 8);
        int kk = f >> 6, c4 = (f & 63) << 2;
        int k = k0 + kk;
        if (k >= K) st[u] = make_float4(0.f, 0.f, 0.f, 0.f);
        else st[u] = (c4 < 128) ? *(const float4*)&ew1[(size_t)k * 128 + c4]
                                : *(const float4*)&ew1[(size_t)(K + k) * 128 + (c4 - 128)];
    }
}

__device__ __forceinline__ void stage_write(float (*buf)[256], const float4 st[4], int tid)
{
    #pragma unroll
    for (int u = 0; u < 4; u++) {
        int f = tid + (u << 8);
        int kk = f >> 6, c4 = (f & 63) << 2;
        *(float4*)&buf[kk][c4] = st[u];
    }
}

// ---------------- PQ GEMMs for edge convs ----------------
__global__ __launch_bounds__(256) void k_pq1(const float* __restrict__ feat,
    const float* __restrict__ x, const float* __restrict__ ew1,
    float* __restrict__ PQ)
{
    __shared__ float aT[288][HPAD];
    __shared__ float wbuf[2][16][256];
    const int tid = threadIdx.x;
    const int tx = tid & 31, ty = tid >> 5;
    const int cLo = tx * 4, cHi = 128 + tx * 4, r0 = ty * 8;
    const int row0 = blockIdx.x * 64;
    const int K = 283;
    for (int s = tid; s < 64 * 256; s += 256) {
        int r = s >> 8, k = s & 255;
        aT[k][r] = feat[(size_t)(row0 + r) * 256 + k];
    }
    for (int s = tid; s < 32 * 64; s += 256) {
        int dd = s >> 6, r = s & 63;
        aT[256 + dd][r] = (dd < 27) ? x[(size_t)(row0 + r) * 90 + 63 + dd] : 0.f;
    }
    float4 st[4];
    stage_wpq(ew1, 0, K, st, tid);
    __syncthreads();
    stage_write(wbuf[0], st, tid);
    __syncthreads();

    float acc[8][8];
    #pragma unroll
    for (int i = 0; i < 8; i++)
        #pragma unroll
        for (int j = 0; j < 8; j++) acc[i][j] = 0.f;

    const int nch = (K + 15) >> 4;
    for (int c = 0; c < nch; c++) {
        const int cur = c & 1;
        const bool more = (c + 1 < nch);
        if (more) stage_wpq(ew1, (c + 1) << 4, K, st, tid);
        const float (*wb)[256] = wbuf[cur];
        const int kbase = c << 4;
        #pragma unroll
        for (int kk = 0; kk < 16; kk++) {
            const int k = kbase + kk;
            float4 a0 = *(const float4*)&aT[k][r0];
            float4 a1 = *(const float4*)&aT[k][r0 + 4];
            float4 b0 = *(const float4*)&wb[kk][cLo];
            float4 b1 = *(const float4*)&wb[kk][cHi];
            fma88(acc, a0, a1, b0, b1);
        }
        if (more) stage_write(wbuf[cur ^ 1], st, tid);
        __syncthreads();
    }
    #pragma unroll
    for (int i = 0; i < 8; i++) {
        *(float4*)&PQ[(size_t)(row0 + r0 + i) * 256 + cLo] =
            make_float4(acc[i][0], acc[i][1], acc[i][2], acc[i][3]);
        *(float4*)&PQ[(size_t)(row0 + r0 + i) * 256 + cHi] =
            make_float4(acc[i][4], acc[i][5], acc[i][6], acc[i][7]);
    }
}

__global__ __launch_bounds__(256) void k_pq2(const float* __restrict__ d1,
    const float* __restrict__ ew1, float* __restrict__ PQ)
{
    __shared__ float aT[128][HPAD];
    __shared__ float wbuf[2][16][256];
    const int tid = threadIdx.x;
    const int tx = tid & 31, ty = tid >> 5;
    const int cLo = tx * 4, cHi = 128 + tx * 4, r0 = ty * 8;
    const int row0 = blockIdx.x * 64;
    const int K = 128;
    for (int s = tid; s < 64 * 128; s += 256) {
        int r = s >> 7, k = s & 127;
        aT[k][r] = d1[(size_t)(row0 + r) * 128 + k];
    }
    float4 st[4];
    stage_wpq(ew1, 0, K, st, tid);
    __syncthreads();
    stage_write(wbuf[0], st, tid);
    __syncthreads();

    float acc[8][8];
    #pragma unroll
    for (int i = 0; i < 8; i++)
        #pragma unroll
        for (int j = 0; j < 8; j++) acc[i][j] = 0.f;

    for (int c = 0; c < 8; c++) {
        const int cur = c & 1;
        const bool more = (c < 7);
        if (more) stage_wpq(ew1, (c + 1) << 4, K, st, tid);
        const float (*wb)[256] = wbuf[cur];
        const int kbase = c << 4;
        #pragma unroll
        for (int kk = 0; kk < 16; kk++) {
            const int k = kbase + kk;
            float4 a0 = *(const float4*)&aT[k][r0];
            float4 a1 = *(const float4*)&aT[k][r0 + 4];
            float4 b0 = *(const float4*)&wb[kk][cLo];
            float4 b1 = *(const float4*)&wb[kk][cHi];
            fma88(acc, a0, a1, b0, b1);
        }
        if (more) stage_write(wbuf[cur ^ 1], st, tid);
        __syncthreads();
    }
    #pragma unroll
    for (int i = 0; i < 8; i++) {
        *(float4*)&PQ[(size_t)(row0 + r0 + i) * 256 + cLo] =
            make_float4(acc[i][0], acc[i][1], acc[i][2], acc[i][3]);
        *(float4*)&PQ[(size_t)(row0 + r0 + i) * 256 + cHi] =
            make_float4(acc[i][4], acc[i][5], acc[i][6], acc[i][7]);
    }
}

// ---------------- edge conv ----------------
template<int RGB>
__global__ __launch_bounds__(256) void k_edge(const float* __restrict__ PQ,
    const float* __restrict__ b1, const float* __restrict__ w2,
    const float* __restrict__ b2, const int* __restrict__ nbr,
    float* __restrict__ dout,
    const float* __restrict__ wrgb, const float* __restrict__ brgb,
    float* __restrict__ out)
{
    __shared__ float h1T[128][97];
    __shared__ float wb[32][128];
    const int tid = threadIdx.x;
    const int n0 = blockIdx.x * 32;
    {
        const int c = tid & 127, eg = tid >> 7;
        const float bias = b1[c];
        for (int e = eg; e < 96; e += 2) {
            int n = e / 3;
            int jj = e - n * 3;
            int i = n0 + n;
            int j = nbr[(size_t)i * 3 + jj];
            float v = PQ[(size_t)i * 256 + c] + bias
                    + PQ[(size_t)j * 256 + 128 + c] - PQ[(size_t)i * 256 + 128 + c];
            h1T[c][e] = fmaxf(v, 0.f);
        }
    }
    const int cg = tid & 15, rg = tid >> 4;
    const int cLo = cg * 4, cHi = 64 + cg * 4, e0 = rg * 6;
    float acc[6][8];
    #pragma unroll
    for (int m = 0; m < 6; m++)
        #pragma unroll
        for (int j = 0; j < 8; j++) acc[m][j] = 0.f;
    for (int k0 = 0; k0 < 128; k0 += 32) {
        __syncthreads();
        for (int s = tid; s < 32 * 128; s += 256) {
            int kk = s >> 7, c = s & 127;
            wb[kk][c] = w2[(size_t)(k0 + kk) * 128 + c];
        }
        __syncthreads();
        for (int kk = 0; kk < 32; kk++) {
            const int k = k0 + kk;
            float av[6];
            #pragma unroll
            for (int m = 0; m < 6; m++) av[m] = h1T[k][e0 + m];
            float4 w0v = *(const float4*)&wb[kk][cLo];
            float4 w1v = *(const float4*)&wb[kk][cHi];
            float bv[8] = {w0v.x,w0v.y,w0v.z,w0v.w,w1v.x,w1v.y,w1v.z,w1v.w};
            #pragma unroll
            for (int m = 0; m < 6; m++)
                #pragma unroll
                for (int j = 0; j < 8; j++)
                    acc[m][j] = fmaf(av[m], bv[j], acc[m][j]);
        }
    }
    float bb[8];
    #pragma unroll
    for (int j = 0; j < 8; j++) bb[j] = b2[(j < 4) ? (cLo + j) : (cHi + j - 4)];
    float dA[8], dB[8];
    #pragma unroll
    for (int j = 0; j < 8; j++) {
        float h0 = fmaxf(acc[0][j] + bb[j], 0.f);
        float h1 = fmaxf(acc[1][j] + bb[j], 0.f);
        float h2 = fmaxf(acc[2][j] + bb[j], 0.f);
        float h3 = fmaxf(acc[3][j] + bb[j], 0.f);
        float h4 = fmaxf(acc[4][j] + bb[j], 0.f);
        float h5 = fmaxf(acc[5][j] + bb[j], 0.f);
        dA[j] = (h0 + h1 + h2) * (1.f / 3.f);
        dB[j] = (h3 + h4 + h5) * (1.f / 3.f);
    }
    if (!RGB) {
        *(float4*)&dout[(size_t)(n0 + 2*rg) * 128 + cLo] = make_float4(dA[0], dA[1], dA[2], dA[3]);
        *(float4*)&dout[(size_t)(n0 + 2*rg) * 128 + cHi] = make_float4(dA[4], dA[5], dA[6], dA[7]);
        *(float4*)&dout[(size_t)(n0 + 2*rg + 1) * 128 + cLo] = make_float4(dB[0], dB[1], dB[2], dB[3]);
        *(float4*)&dout[(size_t)(n0 + 2*rg + 1) * 128 + cHi] = make_float4(dB[4], dB[5], dB[6], dB[7]);
    } else {
        __syncthreads();
        float* d2L = &h1T[0][0];
        #pragma unroll
        for (int j = 0; j < 4; j++) {
            d2L[(2*rg)     * 130 + cLo + j] = dA[j];
            d2L[(2*rg)     * 130 + cHi + j] = dA[j + 4];
            d2L[(2*rg + 1) * 130 + cLo + j] = dB[j];
            d2L[(2*rg + 1) * 130 + cHi + j] = dB[j + 4];
        }
        __syncthreads();
        if (tid < 96) {
            int n = tid / 3, ch = tid - 3 * (tid / 3);
            float s = brgb[ch];
            for (int k = 0; k < 128; k++) s = fmaf(d2L[n * 130 + k], wrgb[k * 3 + ch], s);
            out[(size_t)(n0 + n) * 4 + ch] = 1.f / (1.f + expf(-s));
        }
    }
}

// ---------------- launch ----------------
extern "C" void kernel_launch(void* const* d_in, const int* in_sizes, int n_in,
                              void* d_out, int out_size, void* d_ws, size_t ws_size,
                              hipStream_t stream)
{
    const float* x     = (const float*)d_in[0];
    const int*   bid   = (const int*)d_in[1];
    const float* w0    = (const float*)d_in[2];
    const float* b0    = (const float*)d_in[3];
    const float* wmid  = (const float*)d_in[4];
    const float* bmid  = (const float*)d_in[5];
    const float* wskip = (const float*)d_in[6];
    const float* bskip = (const float*)d_in[7];
    const float* wfin  = (const float*)d_in[8];
    const float* bfin  = (const float*)d_in[9];
    const float* wsig  = (const float*)d_in[10];
    const float* bsig  = (const float*)d_in[11];
    const float* e1w1  = (const float*)d_in[12];
    const float* e1b1  = (const float*)d_in[13];
    const float* e1w2  = (const float*)d_in[14];
    const float* e1b2  = (const float*)d_in[15];
    const float* e2w1  = (const float*)d_in[16];
    const float* e2b1  = (const float*)d_in[17];
    const float* e2w2  = (const float*)d_in[18];
    const float* e2b2  = (const float*)d_in[19];
    const float* wrgb  = (const float*)d_in[20];
    const float* brgb  = (const float*)d_in[21];
    float* out = (float*)d_out;

    char* ws = (char*)d_ws;
    int* cnt = (int*)ws;
    int* grp = (int*)(ws + 256);
    int* nbr = (int*)(ws + 256 + NGRP * GSZ * 4);
    float* bufA = (float*)(ws + (1 << 20));                // 41.9 MB
    float* bufB = bufA + (size_t)B_TOTAL * 256;            // 41.9 MB

    unsigned short* xbh = (unsigned short*)bufA;
    unsigned short* xbl = xbh + (size_t)B_TOTAL * 64;
    float* cn   = (float*)(xbl + (size_t)B_TOTAL * 64);
    float* pval = cn + B_TOTAL;
    int*   pidx = (int*)(pval + (size_t)B_TOTAL * CPART * 3);
    unsigned short* wfrag = (unsigned short*)((char*)bufB + ((size_t)39 << 20));

    hipMemsetAsync(cnt, 0, 256, stream);
    k_scatter<<<B_TOTAL / 256, 256, 0, stream>>>(bid, grp, cnt);
    k_wprep<<<(557056 + 255) / 256, 256, 0, stream>>>(w0, wmid, wskip, wfin, wfrag);
    k_gather<<<dim3(GSZ / 128, NGRP), 256, 0, stream>>>(x, grp, xbh, xbl, cn);
    k_knn_mfma<<<dim3(GSZ / 64, CPART, NGRP), 256, 0, stream>>>(xbh, xbl, cn, pval, pidx);
    k_knn_merge<<<(NGRP * GSZ + 255) / 256, 256, 0, stream>>>(pval, pidx, grp, nbr);
    k_trunk_mfma<<<B_TOTAL / 32, 256, 0, stream>>>(x, wfrag, b0, bmid, bskip, bfin,
                                                   wsig, bsig, bufA, out);
    k_pq1<<<B_TOTAL / 64, 256, 0, stream>>>(bufA, x, e1w1, bufB);
    k_edge<0><<<B_TOTAL / 32, 256, 0, stream>>>(bufB, e1b1, e1w2, e1b2, nbr, bufA,
                                                nullptr, nullptr, nullptr);
    k_pq2<<<B_TOTAL / 64, 256, 0, stream>>>(bufA, e2w1, bufB);
    k_edge<1><<<B_TOTAL / 32, 256, 0, stream>>>(bufB, e2b1, e2w2, e2b2, nbr, nullptr,
                                                wrgb, brgb, out);
}